// Round 7
// baseline (2007.855 us; speedup 1.0000x reference)
//
#include <hip/hip_runtime.h>
#include <math.h>

// B=256, N_ROIS=200, ROI_DIM=199, D=192, H=6, Dh=32, L=3, FF=576, NCLS=2
// T = 51200 tokens.
// GEMMs: bf16x3 split-precision MFMA (Ah*Bh + Ah*Bl + Al*Bh, fp32 accum).
// Activations: packed u32 per element = bf16hi<<16 | bf16lo.
// GEMM epilogue: LDS transpose -> fully-coalesced dwordx4 row-major stores
// (fixes 2.75x HBM write amplification from scattered 64-B half-line stores).

typedef unsigned short u16;
typedef unsigned int u32;
typedef __attribute__((ext_vector_type(8))) __bf16 bf16x8;
typedef __attribute__((ext_vector_type(4))) float f32x4;

#define PERM_HI 0x07060302u
#define PERM_LO 0x05040100u

__device__ __forceinline__ u16 f2bf(float x) {
    u32 u = __float_as_uint(x);
    u = (u + 0x7FFFu + ((u >> 16) & 1u)) >> 16;   // RNE
    return (u16)u;
}
__device__ __forceinline__ float bf2f(u16 h) {
    return __uint_as_float(((u32)h) << 16);
}
__device__ __forceinline__ u32 packpair(float x) {
    u32 u = __float_as_uint(x);
    u32 t = (u + 0x7FFFu + ((u >> 16) & 1u)) & 0xFFFF0000u;   // bf16(x)<<16
    float lo = x - __uint_as_float(t);
    return t | (__float_as_uint(lo) >> 16);
}
__device__ __forceinline__ float unpackf(u32 p) {
    return __uint_as_float(p & 0xFFFF0000u) + __uint_as_float(p << 16);
}

__device__ __forceinline__ float gelu_exact(float x) {
    return 0.5f * x * (1.0f + erff(x * 0.7071067811865475f));
}

__device__ __forceinline__ float wave_sum(float v) {
#pragma unroll
    for (int o = 32; o > 0; o >>= 1) v += __shfl_xor(v, o, 64);
    return v;
}
__device__ __forceinline__ float wave_max(float v) {
#pragma unroll
    for (int o = 32; o > 0; o >>= 1) v = fmaxf(v, __shfl_xor(v, o, 64));
    return v;
}

__device__ __forceinline__ f32x4 mfma_bf16(bf16x8 a, bf16x8 b, f32x4 c) {
    return __builtin_amdgcn_mfma_f32_16x16x32_bf16(a, b, c, 0, 0, 0);
}

// unpack 8 packed u32 (two uint4) -> hi uint4 + lo uint4 (8 bf16 each)
__device__ __forceinline__ void unpack8(uint4 p0, uint4 p1, uint4& hi, uint4& lo) {
    hi.x = __builtin_amdgcn_perm(p0.y, p0.x, PERM_HI);
    hi.y = __builtin_amdgcn_perm(p0.w, p0.z, PERM_HI);
    hi.z = __builtin_amdgcn_perm(p1.y, p1.x, PERM_HI);
    hi.w = __builtin_amdgcn_perm(p1.w, p1.z, PERM_HI);
    lo.x = __builtin_amdgcn_perm(p0.y, p0.x, PERM_LO);
    lo.y = __builtin_amdgcn_perm(p0.w, p0.z, PERM_LO);
    lo.z = __builtin_amdgcn_perm(p1.y, p1.x, PERM_LO);
    lo.w = __builtin_amdgcn_perm(p1.w, p1.z, PERM_LO);
}

// ---------------------------------------------------------------------------
// Weight prep: W fp32 [K,N] (blockIdx.z batches) -> transposed bf16 hi/lo [N][K]
// ---------------------------------------------------------------------------
__global__ void conv_wt(const float* __restrict__ W, u16* __restrict__ oh,
                        u16* __restrict__ ol, int K, int N)
{
    const long z = blockIdx.z;
    const int idx = blockIdx.x * 256 + threadIdx.x;
    if (idx >= K * N) return;
    const int k = idx / N, n = idx - k * N;
    const float x = W[z * K * N + idx];
    const u16 h = f2bf(x);
    const u16 l = f2bf(x - bf2f(h));
    oh[z * (long)K * N + (long)n * K + k] = h;
    ol[z * (long)K * N + (long)n * K + k] = l;
}

// ---------------------------------------------------------------------------
// bf16x3 MFMA GEMM: C[M,N] = A[M,K] @ (Bh+Bl)[N,K]^T + bias
// A: packed u32 (AF32=false) or fp32 split during staging (AF32=true).
// Tile 128x192, BK=32, 256 threads = 4 waves on M.
// EPI 0: fp32 C.  EPI 2: gelu -> packed.  EPI 3: packed.
// Epilogue goes through LDS so global stores are row-major dwordx4.
// ---------------------------------------------------------------------------
template<int EPI, bool AF32>
__global__ __launch_bounds__(256, 3) void gemm_mfma(
    const u32* __restrict__ Ap, const float* __restrict__ Af,
    const u16* __restrict__ Bh, const u16* __restrict__ Bl,
    const float* __restrict__ bias,
    float* __restrict__ C, u32* __restrict__ Cp,
    int N, int K)
{
    __shared__ __align__(16) char smem[51200];
    u16 (*Ash)[40] = (u16 (*)[40])(smem);            // 128x40x2 = 10240
    u16 (*Als)[40] = (u16 (*)[40])(smem + 10240);    // 10240
    u16 (*Bsh)[40] = (u16 (*)[40])(smem + 20480);    // 192x40x2 = 15360
    u16 (*Bsl)[40] = (u16 (*)[40])(smem + 35840);    // 15360 -> 51200

    const int tid = threadIdx.x;
    const int wave = tid >> 6, lane = tid & 63;
    const int lm = lane & 15, quad = lane >> 4;
    const long m0 = (long)blockIdx.x * 128;
    const int n0 = blockIdx.y * 192;

    const int ra = tid >> 1, rk = (tid & 1) * 16;
    const u32* pAp = Ap + (m0 + ra) * K + rk;
    const float* pAf = Af + (m0 + ra) * K + rk;
    const int b0r = tid >> 1, b0k = (tid & 1) * 16;
    const int b1r = b0r + 128;
    const u16* pBh0 = Bh + (long)(n0 + b0r) * K + b0k;
    const u16* pBl0 = Bl + (long)(n0 + b0r) * K + b0k;
    const u16* pBh1 = Bh + (long)(n0 + b1r) * K + b0k;
    const u16* pBl1 = Bl + (long)(n0 + b1r) * K + b0k;
    const bool hasB1 = (tid < 128);

    f32x4 acc[2][12];
#pragma unroll
    for (int i = 0; i < 2; i++)
#pragma unroll
        for (int j = 0; j < 12; j++)
#pragma unroll
            for (int r = 0; r < 4; r++) acc[i][j][r] = 0.f;

    uint4 tA0, tA1, tA2, tA3;
    uint4 tB0[4], tB1[4];

    auto load_tiles = [&](int k0) {
        if (AF32) {
            tA0 = *(const uint4*)(pAf + k0);
            tA1 = *(const uint4*)(pAf + k0 + 4);
            tA2 = *(const uint4*)(pAf + k0 + 8);
            tA3 = *(const uint4*)(pAf + k0 + 12);
        } else {
            tA0 = *(const uint4*)(pAp + k0);
            tA1 = *(const uint4*)(pAp + k0 + 4);
            tA2 = *(const uint4*)(pAp + k0 + 8);
            tA3 = *(const uint4*)(pAp + k0 + 12);
        }
        tB0[0] = *(const uint4*)(pBh0 + k0);
        tB0[1] = *(const uint4*)(pBh0 + k0 + 8);
        tB0[2] = *(const uint4*)(pBl0 + k0);
        tB0[3] = *(const uint4*)(pBl0 + k0 + 8);
        if (hasB1) {
            tB1[0] = *(const uint4*)(pBh1 + k0);
            tB1[1] = *(const uint4*)(pBh1 + k0 + 8);
            tB1[2] = *(const uint4*)(pBl1 + k0);
            tB1[3] = *(const uint4*)(pBl1 + k0 + 8);
        }
    };

    auto store_tiles = [&]() {
        if (AF32) {
            u32 fb[16];
            *(uint4*)&fb[0] = tA0; *(uint4*)&fb[4] = tA1;
            *(uint4*)&fb[8] = tA2; *(uint4*)&fb[12] = tA3;
            u32 hw[8], lw[8];
#pragma unroll
            for (int p = 0; p < 8; p++) {
                const u32 u0 = fb[2 * p], u1 = fb[2 * p + 1];
                const u32 t0 = (u0 + 0x7FFFu + ((u0 >> 16) & 1u)) & 0xFFFF0000u;
                const u32 t1 = (u1 + 0x7FFFu + ((u1 >> 16) & 1u)) & 0xFFFF0000u;
                const float l0 = __uint_as_float(u0) - __uint_as_float(t0);
                const float l1 = __uint_as_float(u1) - __uint_as_float(t1);
                hw[p] = (t0 >> 16) | t1;
                lw[p] = (__float_as_uint(l0) >> 16) |
                        (__float_as_uint(l1) & 0xFFFF0000u);
            }
            *(uint4*)&Ash[ra][rk] = *(uint4*)&hw[0];
            *(uint4*)&Ash[ra][rk + 8] = *(uint4*)&hw[4];
            *(uint4*)&Als[ra][rk] = *(uint4*)&lw[0];
            *(uint4*)&Als[ra][rk + 8] = *(uint4*)&lw[4];
        } else {
            uint4 h0, l0, h1, l1;
            unpack8(tA0, tA1, h0, l0);
            unpack8(tA2, tA3, h1, l1);
            *(uint4*)&Ash[ra][rk] = h0;
            *(uint4*)&Ash[ra][rk + 8] = h1;
            *(uint4*)&Als[ra][rk] = l0;
            *(uint4*)&Als[ra][rk + 8] = l1;
        }
        *(uint4*)&Bsh[b0r][b0k] = tB0[0];
        *(uint4*)&Bsh[b0r][b0k + 8] = tB0[1];
        *(uint4*)&Bsl[b0r][b0k] = tB0[2];
        *(uint4*)&Bsl[b0r][b0k + 8] = tB0[3];
        if (hasB1) {
            *(uint4*)&Bsh[b1r][b0k] = tB1[0];
            *(uint4*)&Bsh[b1r][b0k + 8] = tB1[1];
            *(uint4*)&Bsl[b1r][b0k] = tB1[2];
            *(uint4*)&Bsl[b1r][b0k + 8] = tB1[3];
        }
    };

    const int kt = K >> 5;
    load_tiles(0);
    store_tiles();
    __syncthreads();

    for (int t = 0; t < kt; t++) {
        if (t + 1 < kt) load_tiles((t + 1) << 5);

        bf16x8 afh[2], afl[2];
#pragma unroll
        for (int mi = 0; mi < 2; mi++) {
            afh[mi] = *(const bf16x8*)&Ash[wave * 32 + mi * 16 + lm][quad * 8];
            afl[mi] = *(const bf16x8*)&Als[wave * 32 + mi * 16 + lm][quad * 8];
        }
#pragma unroll
        for (int g = 0; g < 4; g++) {
            bf16x8 bfh[3], bfl[3];
#pragma unroll
            for (int j = 0; j < 3; j++) {
                bfh[j] = *(const bf16x8*)&Bsh[g * 48 + j * 16 + lm][quad * 8];
                bfl[j] = *(const bf16x8*)&Bsl[g * 48 + j * 16 + lm][quad * 8];
            }
#pragma unroll
            for (int mi = 0; mi < 2; mi++)
#pragma unroll
                for (int j = 0; j < 3; j++) {
                    const int ni = g * 3 + j;
                    acc[mi][ni] = mfma_bf16(afh[mi], bfh[j], acc[mi][ni]);
                    acc[mi][ni] = mfma_bf16(afh[mi], bfl[j], acc[mi][ni]);
                    acc[mi][ni] = mfma_bf16(afl[mi], bfh[j], acc[mi][ni]);
                }
        }
        if (t + 1 < kt) {
            __syncthreads();
            store_tiles();
            __syncthreads();
        }
    }

    // ---- epilogue via LDS transpose -> coalesced dwordx4 stores ----
    __syncthreads();                      // staging LDS now dead, reuse it
    u32 (*ep)[196] = (u32 (*)[196])smem;  // 64 x 196 x 4 = 50176 B
#pragma unroll
    for (int mi = 0; mi < 2; mi++) {
#pragma unroll
        for (int ni = 0; ni < 12; ni++) {
            const int col = n0 + ni * 16 + lm;
            const float bv = bias[col];
#pragma unroll
            for (int r = 0; r < 4; r++) {
                float v = acc[mi][ni][r] + bv;
                u32 bits;
                if (EPI == 0) {
                    bits = __float_as_uint(v);
                } else {
                    if (EPI == 2) v = gelu_exact(v);
                    bits = packpair(v);
                }
                ep[wave * 16 + quad * 4 + r][ni * 16 + lm] = bits;
            }
        }
        __syncthreads();
#pragma unroll
        for (int it = 0; it < 12; it++) {
            const int c = tid + it * 256;           // 0..3071
            const int er = c / 48;                  // ep row 0..63
            const int cc = (c - er * 48) * 4;       // col 0..188 step 4
            const long grow = m0 + (er >> 4) * 32 + mi * 16 + (er & 15);
            const uint4 v = *(const uint4*)&ep[er][cc];
            if (EPI == 0)
                *(uint4*)&C[grow * N + n0 + cc] = v;
            else
                *(uint4*)&Cp[grow * N + n0 + cc] = v;
        }
        __syncthreads();
    }
}

// ---------------------------------------------------------------------------
// fp32 GEMM (tokenizer batched + tiny pool GEMMs). Tile 128x64, BK=16.
// ---------------------------------------------------------------------------
template<int EPI>
__global__ __launch_bounds__(256) void gemm_kernel(
    const float* __restrict__ A, int lda, long strideA,
    const float* __restrict__ Bw, long strideB,
    const float* __restrict__ bias, long strideBias,
    float* __restrict__ C, int ldc, long strideC,
    int M, int N, int K, int ldb)
{
    __shared__ float As[16][132];
    __shared__ float Bs[16][68];

    const int z = blockIdx.z;
    const float* Ab    = A    + (long)z * strideA;
    const float* Bb    = Bw   + (long)z * strideB;
    const float* biasb = bias + (long)z * strideBias;
    float*       Cb    = C    + (long)z * strideC;

    const int row0 = blockIdx.x * 128;
    const int col0 = blockIdx.y * 64;
    const int tid  = threadIdx.x;
    const int tm = tid >> 4;
    const int tn = tid & 15;

    const int la_m = tid >> 1;
    const int la_k = (tid & 1) * 8;
    const int lb_k = tid >> 4;
    const int lb_n = (tid & 15) * 4;

    const float* bcol = Bb + (col0 + lb_n);
    const float* arow = Ab + (long)(row0 + la_m) * lda;
    const bool vecA = ((lda & 3) == 0) &&
                      ((((unsigned long long)(const void*)arow) & 15ull) == 0ull);

    float acc[8][4];
#pragma unroll
    for (int i = 0; i < 8; i++)
#pragma unroll
        for (int j = 0; j < 4; j++) acc[i][j] = 0.f;

    for (int k0 = 0; k0 < K; k0 += 16) {
        if (vecA && (k0 + 16 <= K)) {
            float4 v0 = *(const float4*)(arow + k0 + la_k);
            float4 v1 = *(const float4*)(arow + k0 + la_k + 4);
            As[la_k + 0][la_m] = v0.x; As[la_k + 1][la_m] = v0.y;
            As[la_k + 2][la_m] = v0.z; As[la_k + 3][la_m] = v0.w;
            As[la_k + 4][la_m] = v1.x; As[la_k + 5][la_m] = v1.y;
            As[la_k + 6][la_m] = v1.z; As[la_k + 7][la_m] = v1.w;
        } else {
#pragma unroll
            for (int i = 0; i < 8; i++) {
                int k = k0 + la_k + i;
                As[la_k + i][la_m] = (k < K) ? arow[k] : 0.f;
            }
        }
        {
            int k = k0 + lb_k;
            float4 v = make_float4(0.f, 0.f, 0.f, 0.f);
            if (k < K) v = *(const float4*)(bcol + (long)k * ldb);
            *(float4*)&Bs[lb_k][lb_n] = v;
        }
        __syncthreads();
#pragma unroll
        for (int kk = 0; kk < 16; kk++) {
            float4 a0 = *(const float4*)&As[kk][tm * 8];
            float4 a1 = *(const float4*)&As[kk][tm * 8 + 4];
            float4 b4 = *(const float4*)&Bs[kk][tn * 4];
            float av[8] = {a0.x, a0.y, a0.z, a0.w, a1.x, a1.y, a1.z, a1.w};
            float bv[4] = {b4.x, b4.y, b4.z, b4.w};
#pragma unroll
            for (int i = 0; i < 8; i++)
#pragma unroll
                for (int j = 0; j < 4; j++) acc[i][j] += av[i] * bv[j];
        }
        __syncthreads();
    }

    const int gcol = col0 + tn * 4;
    float4 bv4 = *(const float4*)(biasb + gcol);
#pragma unroll
    for (int i = 0; i < 8; i++) {
        int grow = row0 + tm * 8 + i;
        float4 o;
        o.x = acc[i][0] + bv4.x; o.y = acc[i][1] + bv4.y;
        o.z = acc[i][2] + bv4.z; o.w = acc[i][3] + bv4.w;
        if (EPI == 1) {
            o.x = gelu_exact(o.x); o.y = gelu_exact(o.y);
            o.z = gelu_exact(o.z); o.w = gelu_exact(o.w);
        }
        *(float4*)(Cb + (long)grow * ldc + gcol) = o;
    }
}

// ---------------------------------------------------------------------------
// tokenizer post: h = gelu(LN(src; g[r],b[r])) + pos[r] -> packed
// ---------------------------------------------------------------------------
__global__ __launch_bounds__(64) void tok_ln_pack(
    const float* __restrict__ src, u32* __restrict__ hp,
    const float* __restrict__ g, const float* __restrict__ bt,
    const float* __restrict__ pos)
{
    const long row = blockIdx.x;
    const int r = (int)(row % 200);
    const int l = threadIdx.x;
    const float* sp = src + row * 192;
    float x0 = sp[l], x1 = sp[l + 64], x2 = sp[l + 128];
    float m = wave_sum(x0 + x1 + x2) * (1.f / 192.f);
    float d0 = x0 - m, d1 = x1 - m, d2 = x2 - m;
    float v = wave_sum(d0 * d0 + d1 * d1 + d2 * d2) * (1.f / 192.f);
    float rs = 1.f / sqrtf(v + 1e-5f);
    const float* gr = g + r * 192;
    const float* br = bt + r * 192;
    const float* pr = pos + r * 192;
    const long base = row * 192;
#pragma unroll
    for (int i = 0; i < 3; i++) {
        const int c = l + 64 * i;
        const float d = (i == 0) ? d0 : (i == 1) ? d1 : d2;
        const float y = gelu_exact(d * rs * gr[c] + br[c]) + pr[c];
        hp[base + c] = packpair(y);
    }
}

// ---------------------------------------------------------------------------
// h = LN(h + a; g, b) -> packed, in place.
// ---------------------------------------------------------------------------
__global__ __launch_bounds__(64) void resid_ln_pack(
    u32* __restrict__ hp, const float* __restrict__ a,
    const float* __restrict__ g, const float* __restrict__ bt)
{
    const long row = blockIdx.x;
    const int l = threadIdx.x;
    const long base = row * 192;
    float x0 = unpackf(hp[base + l])       + a[base + l];
    float x1 = unpackf(hp[base + l + 64])  + a[base + l + 64];
    float x2 = unpackf(hp[base + l + 128]) + a[base + l + 128];
    float m = wave_sum(x0 + x1 + x2) * (1.f / 192.f);
    float d0 = x0 - m, d1 = x1 - m, d2 = x2 - m;
    float v = wave_sum(d0 * d0 + d1 * d1 + d2 * d2) * (1.f / 192.f);
    float rs = 1.f / sqrtf(v + 1e-5f);
#pragma unroll
    for (int i = 0; i < 3; i++) {
        const int c = l + 64 * i;
        const float d = (i == 0) ? d0 : (i == 1) ? d1 : d2;
        hp[base + c] = packpair(d * rs * g[c] + bt[c]);
    }
}

// ---------------------------------------------------------------------------
// MFMA flash encoder attention. One block per (b,h); 4 waves.
// qkvp: [T,576] packed (q|k|v, each [6][32]).  out: fp32 [T,192].
// ---------------------------------------------------------------------------
__global__ __launch_bounds__(256, 2) void attn_enc_mfma(
    const u32* __restrict__ qkvp, float* __restrict__ out)
{
    __shared__ u16 Ksh[96][40];
    __shared__ u16 Ksl[96][40];
    __shared__ u16 Vth[32][120];
    __shared__ u16 Vtl[32][120];
    __shared__ u32 Pbuf[4][16][108];

    const int bh = blockIdx.x;
    const int b = bh / 6, h = bh % 6;
    const int tid = threadIdx.x;
    const int wave = tid >> 6, lane = tid & 63;
    const int lm = lane & 15, quad = lane >> 4;
    const int nq = (wave == 0) ? 4 : 3;   // q-tiles: wave + 4*i (13 total)

    // ---- Q fragments (A-layout: m=lm, k=quad*8+j) ----
    uint4 qh[4], ql[4];
#pragma unroll
    for (int i = 0; i < 4; i++) {
        if (i < nq) {
            int qt = wave + 4 * i;
            int qrow = qt * 16 + lm; if (qrow > 199) qrow = 199;
            const long off = (long)(b * 200 + qrow) * 576 + h * 32 + quad * 8;
            uint4 p0 = *(const uint4*)(qkvp + off);
            uint4 p1 = *(const uint4*)(qkvp + off + 4);
            unpack8(p0, p1, qh[i], ql[i]);
        }
    }

    float mrow[4][4], lrow[4][4];
    f32x4 accO[4][2];
#pragma unroll
    for (int i = 0; i < 4; i++)
#pragma unroll
        for (int r = 0; r < 4; r++) {
            mrow[i][r] = -1e30f; lrow[i][r] = 0.f;
            accO[i][0][r] = 0.f; accO[i][1][r] = 0.f;
        }

    const float scale = 0.17677669529663688f;   // 1/sqrt(32)

#pragma unroll
    for (int ph = 0; ph < 3; ph++) {
        const int base = (ph == 0) ? 0 : (ph == 1) ? 96 : 192;
        const int ntl  = (ph == 2) ? 2 : 6;      // 16-key S tiles
        const int nck  = (ph == 2) ? 1 : 3;      // 32-key PV chunks
        const int nslot = ntl * 16;

        __syncthreads();
        if (tid < nslot) {
            const int key = base + tid;
            const bool valid = key < 200;
            const long roff = (long)(b * 200 + (valid ? key : 0)) * 576 + h * 32;
            uint4 z4 = make_uint4(0, 0, 0, 0);
#pragma unroll
            for (int u = 0; u < 4; u++) {
                uint4 kp0 = valid ? *(const uint4*)(qkvp + roff + 192 + u * 8) : z4;
                uint4 kp1 = valid ? *(const uint4*)(qkvp + roff + 192 + u * 8 + 4) : z4;
                uint4 kh, kl;
                unpack8(kp0, kp1, kh, kl);
                *(uint4*)&Ksh[tid][u * 8] = kh;
                *(uint4*)&Ksl[tid][u * 8] = kl;
                uint4 vp0 = valid ? *(const uint4*)(qkvp + roff + 384 + u * 8) : z4;
                uint4 vp1 = valid ? *(const uint4*)(qkvp + roff + 384 + u * 8 + 4) : z4;
                uint4 vh, vl;
                unpack8(vp0, vp1, vh, vl);
                const u16* vhp = (const u16*)&vh;
                const u16* vlp = (const u16*)&vl;
#pragma unroll
                for (int j = 0; j < 8; j++) {
                    Vth[u * 8 + j][tid] = vhp[j];
                    Vtl[u * 8 + j][tid] = vlp[j];
                }
            }
        }
        __syncthreads();

#pragma unroll
        for (int i = 0; i < 4; i++) {
            if (i >= nq) continue;
            const bf16x8 qhf = *(const bf16x8*)&qh[i];
            const bf16x8 qlf = *(const bf16x8*)&ql[i];
            float s[6][4];
#pragma unroll
            for (int ni = 0; ni < 6; ni++) {
                if (ni >= ntl) continue;
                bf16x8 kh8 = *(const bf16x8*)&Ksh[ni * 16 + lm][quad * 8];
                bf16x8 kl8 = *(const bf16x8*)&Ksl[ni * 16 + lm][quad * 8];
                f32x4 c = {0.f, 0.f, 0.f, 0.f};
                c = mfma_bf16(qhf, kh8, c);
                c = mfma_bf16(qhf, kl8, c);
                c = mfma_bf16(qlf, kh8, c);
                const bool masked = (base + ni * 16 + lm) >= 200;
#pragma unroll
                for (int r = 0; r < 4; r++)
                    s[ni][r] = masked ? -1e30f : c[r] * scale;
            }
            // online softmax per row (rows quad*4+r)
            float fac[4];
#pragma unroll
            for (int r = 0; r < 4; r++) {
                float pm = s[0][r];
#pragma unroll
                for (int ni = 1; ni < 6; ni++)
                    if (ni < ntl) pm = fmaxf(pm, s[ni][r]);
                pm = fmaxf(pm, __shfl_xor(pm, 1, 64));
                pm = fmaxf(pm, __shfl_xor(pm, 2, 64));
                pm = fmaxf(pm, __shfl_xor(pm, 4, 64));
                pm = fmaxf(pm, __shfl_xor(pm, 8, 64));
                const float mn = fmaxf(mrow[i][r], pm);
                fac[r] = __expf(mrow[i][r] - mn);
                mrow[i][r] = mn;
                float ps = 0.f;
#pragma unroll
                for (int ni = 0; ni < 6; ni++) {
                    if (ni >= ntl) continue;
                    float e = __expf(s[ni][r] - mn);
                    s[ni][r] = e;
                    ps += e;
                }
                ps += __shfl_xor(ps, 1, 64);
                ps += __shfl_xor(ps, 2, 64);
                ps += __shfl_xor(ps, 4, 64);
                ps += __shfl_xor(ps, 8, 64);
                lrow[i][r] = lrow[i][r] * fac[r] + ps;
                accO[i][0][r] *= fac[r];
                accO[i][1][r] *= fac[r];
            }
            // write P (packed hi|lo) to Pbuf
#pragma unroll
            for (int ni = 0; ni < 6; ni++) {
                if (ni >= ntl) continue;
#pragma unroll
                for (int r = 0; r < 4; r++) {
                    Pbuf[wave][quad * 4 + r][ni * 16 + lm] = packpair(s[ni][r]);
                }
            }
            // PV
#pragma unroll
            for (int ck = 0; ck < 3; ck++) {
                if (ck >= nck) continue;
                uint4 w01 = *(const uint4*)&Pbuf[wave][lm][ck * 32 + quad * 8];
                uint4 w23 = *(const uint4*)&Pbuf[wave][lm][ck * 32 + quad * 8 + 4];
                uint4 hiu, lou;
                unpack8(w01, w23, hiu, lou);
                const bf16x8 phf = *(const bf16x8*)&hiu;
                const bf16x8 plf = *(const bf16x8*)&lou;
#pragma unroll
                for (int nt = 0; nt < 2; nt++) {
                    bf16x8 vh8 = *(const bf16x8*)&Vth[nt * 16 + lm][ck * 32 + quad * 8];
                    bf16x8 vl8 = *(const bf16x8*)&Vtl[nt * 16 + lm][ck * 32 + quad * 8];
                    accO[i][nt] = mfma_bf16(phf, vh8, accO[i][nt]);
                    accO[i][nt] = mfma_bf16(plf, vh8, accO[i][nt]);
                    accO[i][nt] = mfma_bf16(phf, vl8, accO[i][nt]);
                }
            }
        }
    }

    // epilogue: O row = qt*16 + quad*4 + r, col = h*32 + nt*16 + lm
#pragma unroll
    for (int i = 0; i < 4; i++) {
        if (i >= nq) continue;
        const int qt = wave + 4 * i;
#pragma unroll
        for (int r = 0; r < 4; r++) {
            const int qrow = qt * 16 + quad * 4 + r;
            if (qrow >= 200) continue;
            const float inv = 1.f / lrow[i][r];
            float* op = out + (long)(b * 200 + qrow) * 192 + h * 32 + lm;
            op[0]  = accO[i][0][r] * inv;
            op[16] = accO[i][1][r] * inv;
        }
    }
}

// ---------------------------------------------------------------------------
__global__ __launch_bounds__(192) void mean_tokens_pack(
    const u32* __restrict__ hp, float* __restrict__ qmean)
{
    const int b = blockIdx.x, d = threadIdx.x;
    float s = 0.f;
    for (int r = 0; r < 200; r++) {
        s += unpackf(hp[((long)b * 200 + r) * 192 + d]);
    }
    qmean[b * 192 + d] = s * (1.f / 200.f);
}

// ---------------------------------------------------------------------------
// Pooling attention (fp32): qp [256,192], kv [T,384], out [256,192]
// ---------------------------------------------------------------------------
__global__ __launch_bounds__(64) void attn_pool(
    const float* __restrict__ qp, const float* __restrict__ kv,
    float* __restrict__ out)
{
    __shared__ float p[200];
    const int b = blockIdx.x / 6, h = blockIdx.x % 6;
    const int lane = threadIdx.x;

    const float* qrow = qp + b * 192 + h * 32;
    float qr[32];
#pragma unroll
    for (int u = 0; u < 8; u++) {
        float4 t = *(const float4*)(qrow + 4 * u);
        qr[4 * u] = t.x; qr[4 * u + 1] = t.y;
        qr[4 * u + 2] = t.z; qr[4 * u + 3] = t.w;
    }
    const float scale = 0.17677669529663688f;
    const float* kb = kv + (long)(b * 200) * 384 + h * 32;
    float s[4];
    float mymax = -1e30f;
#pragma unroll
    for (int g = 0; g < 4; g++) {
        int j = lane + 64 * g;
        if (j < 200) {
            const float* kr = kb + (long)j * 384;
            float acc = 0.f;
#pragma unroll
            for (int u = 0; u < 8; u++) {
                float4 k4 = *(const float4*)(kr + 4 * u);
                acc += qr[4 * u] * k4.x + qr[4 * u + 1] * k4.y +
                       qr[4 * u + 2] * k4.z + qr[4 * u + 3] * k4.w;
            }
            s[g] = acc * scale;
            mymax = fmaxf(mymax, s[g]);
        } else {
            s[g] = -1e30f;
        }
    }
    float mx = wave_max(mymax);
    float psum = 0.f;
#pragma unroll
    for (int g = 0; g < 4; g++) {
        int j = lane + 64 * g;
        if (j < 200) {
            float e = __expf(s[g] - mx);
            p[j] = e;
            psum += e;
        }
    }
    float tot = wave_sum(psum);
    __syncthreads();
    const int half = lane >> 5, d = lane & 31;
    const float* vb = kv + (long)(b * 200) * 384 + 192 + h * 32 + d;
    float acc = 0.f;
    for (int jj = 0; jj < 100; jj++) {
        int j = half * 100 + jj;
        acc += p[j] * vb[(long)j * 384];
    }
    acc += __shfl_xor(acc, 32, 64);
    acc /= tot;
    if (lane < 32) out[b * 192 + h * 32 + d] = acc;
}

// ---------------------------------------------------------------------------
__global__ __launch_bounds__(64) void classifier_kernel(
    const float* __restrict__ pooled,
    const float* __restrict__ g, const float* __restrict__ bt,
    const float* __restrict__ W1, const float* __restrict__ b1,
    const float* __restrict__ W2, const float* __restrict__ b2,
    const float* __restrict__ W3, const float* __restrict__ b3,
    float* __restrict__ out)
{
    __shared__ float z[192];
    __shared__ float z1[96];
    __shared__ float z2[48];
    const int b = blockIdx.x, lane = threadIdx.x;
    const float* pr = pooled + b * 192;
    float x0 = pr[lane], x1 = pr[lane + 64], x2 = pr[lane + 128];
    float m = wave_sum(x0 + x1 + x2) * (1.f / 192.f);
    float d0 = x0 - m, d1 = x1 - m, d2 = x2 - m;
    float v = wave_sum(d0 * d0 + d1 * d1 + d2 * d2) * (1.f / 192.f);
    float rs = 1.f / sqrtf(v + 1e-5f);
    z[lane]       = d0 * rs * g[lane]       + bt[lane];
    z[lane + 64]  = d1 * rs * g[lane + 64]  + bt[lane + 64];
    z[lane + 128] = d2 * rs * g[lane + 128] + bt[lane + 128];
    __syncthreads();
#pragma unroll
    for (int rep = 0; rep < 2; rep++) {
        int j = lane + rep * 64;
        if (j < 96) {
            float a = b1[j];
            for (int k = 0; k < 192; k++) a += z[k] * W1[k * 96 + j];
            z1[j] = gelu_exact(a);
        }
    }
    __syncthreads();
    if (lane < 48) {
        float a = b2[lane];
        for (int k = 0; k < 96; k++) a += z1[k] * W2[k * 48 + lane];
        z2[lane] = gelu_exact(a);
    }
    __syncthreads();
    if (lane < 2) {
        float a = b3[lane];
        for (int k = 0; k < 48; k++) a += z2[k] * W3[k * 2 + lane];
        out[b * 2 + lane] = a;
    }
}

// ---------------------------------------------------------------------------
extern "C" void kernel_launch(void* const* d_in, const int* in_sizes, int n_in,
                              void* d_out, int out_size, void* d_ws, size_t ws_size,
                              hipStream_t stream)
{
    (void)in_sizes; (void)n_in; (void)out_size; (void)ws_size;

    const float* x         = (const float*)d_in[0];
    const float* roi_W     = (const float*)d_in[1];
    const float* roi_b     = (const float*)d_in[2];
    const float* roi_ln_g  = (const float*)d_in[3];
    const float* roi_ln_b  = (const float*)d_in[4];
    const float* pos_emb   = (const float*)d_in[5];
    const float* enc_Wqkv  = (const float*)d_in[6];
    const float* enc_bqkv  = (const float*)d_in[7];
    const float* enc_Wo    = (const float*)d_in[8];
    const float* enc_bo    = (const float*)d_in[9];
    const float* enc_ln1_g = (const float*)d_in[10];
    const float* enc_ln1_b = (const float*)d_in[11];
    const float* enc_W1    = (const float*)d_in[12];
    const float* enc_b1    = (const float*)d_in[13];
    const float* enc_W2    = (const float*)d_in[14];
    const float* enc_b2    = (const float*)d_in[15];
    const float* enc_ln2_g = (const float*)d_in[16];
    const float* enc_ln2_b = (const float*)d_in[17];
    const float* pool_Wqkv = (const float*)d_in[18];
    const float* pool_bqkv = (const float*)d_in[19];
    const float* pool_Wo   = (const float*)d_in[20];
    const float* pool_bo   = (const float*)d_in[21];
    const float* cls_ln_g  = (const float*)d_in[22];
    const float* cls_ln_b  = (const float*)d_in[23];
    const float* cls_W1    = (const float*)d_in[24];
    const float* cls_b1    = (const float*)d_in[25];
    const float* cls_W2    = (const float*)d_in[26];
    const float* cls_b2    = (const float*)d_in[27];
    const float* cls_W3    = (const float*)d_in[28];
    const float* cls_b3    = (const float*)d_in[29];

    char* ws = (char*)d_ws;
    u32*   hp    = (u32*)(ws);                      // [T,192] packed, 39,321,600 B
    char*  bufA  = ws + 39321600;                   // 117,964,800 B
    float* bufAf = (float*)bufA;
    u32*   qkvp  = (u32*)bufA;                      // [T,576] packed
    u32*   ffp   = (u32*)bufA;                      // reuse after attn
    char*  bufB  = ws + 157286400;                  // 39,321,600 B
    float* bufBf = (float*)bufB;                    // fp32 [T,192]
    float* qmean = (float*)(ws + 196608000);
    float* qp    = qmean + 49152;
    float* pattn = qp + 49152;
    float* pooled= pattn + 49152;
    char*  wts   = ws + 197394432;
    u16* WqkvH = (u16*)(wts);                 // 3*576*192
    u16* WqkvL = (u16*)(wts + 663552);
    u16* Wff1H = (u16*)(wts + 1327104);       // 3*576*192
    u16* Wff1L = (u16*)(wts + 1990656);
    u16* Wff2H = (u16*)(wts + 2654208);       // 3*192*576
    u16* Wff2L = (u16*)(wts + 3317760);
    u16* WwoH  = (u16*)(wts + 3981312);       // 3*192*192
    u16* WwoL  = (u16*)(wts + 4202496);
    u16* WkvH  = (u16*)(wts + 4423680);       // 384*192
    u16* WkvL  = (u16*)(wts + 4571136);

    // ---- weight split/transpose (once per call) ----
    conv_wt<<<dim3(144, 1, 9), 256, 0, stream>>>(enc_Wqkv, WqkvH, WqkvL, 192, 192);
    conv_wt<<<dim3(432, 1, 3), 256, 0, stream>>>(enc_W1, Wff1H, Wff1L, 192, 576);
    conv_wt<<<dim3(432, 1, 3), 256, 0, stream>>>(enc_W2, Wff2H, Wff2L, 576, 192);
    conv_wt<<<dim3(144, 1, 3), 256, 0, stream>>>(enc_Wo, WwoH, WwoL, 192, 192);
    conv_wt<<<dim3(144, 1, 2), 256, 0, stream>>>(pool_Wqkv + 36864, WkvH, WkvL, 192, 192);

    // ---- tokenizer (fp32) -> bufBf [T,192] ----
    gemm_kernel<0><<<dim3(2, 3, 200), 256, 0, stream>>>(
        x, 39800, 199, roi_W, (long)199 * 192, roi_b, 192,
        bufBf, 38400, 192, 256, 192, 199, 192);
    tok_ln_pack<<<51200, 64, 0, stream>>>(bufBf, hp, roi_ln_g, roi_ln_b, pos_emb);

    // ---- encoder layers ----
    for (int i = 0; i < 3; i++) {
        // qkv packed -> qkvp [T,576]
        gemm_mfma<3, false><<<dim3(400, 3), 256, 0, stream>>>(
            hp, nullptr,
            WqkvH + (long)i * 110592, WqkvL + (long)i * 110592,
            enc_bqkv + i * 576, nullptr, qkvp, 576, 192);
        // MFMA flash attention -> bufBf fp32 [T,192]
        attn_enc_mfma<<<1536, 256, 0, stream>>>(qkvp, bufBf);
        // Wo (fp32 A, in-place) -> bufBf
        gemm_mfma<0, true><<<dim3(400, 1), 256, 0, stream>>>(
            nullptr, bufBf,
            WwoH + (long)i * 36864, WwoL + (long)i * 36864,
            enc_bo + i * 192, bufBf, nullptr, 192, 192);
        resid_ln_pack<<<51200, 64, 0, stream>>>(hp, bufBf,
            enc_ln1_g + i * 192, enc_ln1_b + i * 192);
        // ff1 gelu packed -> ffp [T,576]
        gemm_mfma<2, false><<<dim3(400, 3), 256, 0, stream>>>(
            hp, nullptr,
            Wff1H + (long)i * 110592, Wff1L + (long)i * 110592,
            enc_b1 + i * 576, nullptr, ffp, 576, 192);
        // ff2 -> bufBf fp32
        gemm_mfma<0, false><<<dim3(400, 1), 256, 0, stream>>>(
            ffp, nullptr,
            Wff2H + (long)i * 110592, Wff2L + (long)i * 110592,
            enc_b2 + i * 192, bufBf, nullptr, 192, 576);
        resid_ln_pack<<<51200, 64, 0, stream>>>(hp, bufBf,
            enc_ln2_g + i * 192, enc_ln2_b + i * 192);
    }

    // ---- pooling ----
    mean_tokens_pack<<<256, 192, 0, stream>>>(hp, qmean);
    gemm_kernel<0><<<dim3(2, 3, 1), 256, 0, stream>>>(
        qmean, 192, 0, pool_Wqkv, 0, pool_bqkv, 0, qp, 192, 0, 256, 192, 192, 192);
    gemm_mfma<0, false><<<dim3(400, 2), 256, 0, stream>>>(
        hp, nullptr, WkvH, WkvL, pool_bqkv + 192,
        bufAf, nullptr, 384, 192);
    attn_pool<<<1536, 64, 0, stream>>>(qp, bufAf, pattn);
    gemm_kernel<0><<<dim3(2, 3, 1), 256, 0, stream>>>(
        pattn, 192, 0, pool_Wo, 0, pool_bo, 0, pooled, 192, 0, 256, 192, 192, 192);

    // ---- classifier ----
    classifier_kernel<<<256, 64, 0, stream>>>(
        pooled, cls_ln_g, cls_ln_b,
        cls_W1, cls_b1, cls_W2, cls_b2, cls_W3, cls_b3,
        (float*)d_out);
}

// Round 8
// 1452.198 us; speedup vs baseline: 1.3826x; 1.3826x over previous
//
#include <hip/hip_runtime.h>
#include <math.h>

// B=256, N_ROIS=200, ROI_DIM=199, D=192, H=6, Dh=32, L=3, FF=576, NCLS=2
// T = 51200 tokens.
// GEMMs: bf16x3 split-precision MFMA (Ah*Bh + Ah*Bl + Al*Bh, fp32 accum).
// Activations: separate bf16 hi / lo u16 arrays (GLL-compatible).
// Staging: __builtin_amdgcn_global_load_lds width=16 (async global->LDS,
// no VGPR round-trip) -- the m93->m97 ladder lever.

typedef unsigned short u16;
typedef unsigned int u32;
typedef __attribute__((ext_vector_type(8))) __bf16 bf16x8;
typedef __attribute__((ext_vector_type(4))) float f32x4;

#define GLL16(gp, lp) __builtin_amdgcn_global_load_lds(                 \
    (const __attribute__((address_space(1))) void*)(gp),                \
    (__attribute__((address_space(3))) void*)(lp), 16, 0, 0)

__device__ __forceinline__ u16 f2bf(float x) {
    u32 u = __float_as_uint(x);
    u = (u + 0x7FFFu + ((u >> 16) & 1u)) >> 16;   // RNE
    return (u16)u;
}
__device__ __forceinline__ float bf2f(u16 h) {
    return __uint_as_float(((u32)h) << 16);
}

__device__ __forceinline__ float gelu_exact(float x) {
    return 0.5f * x * (1.0f + erff(x * 0.7071067811865475f));
}

__device__ __forceinline__ float wave_sum(float v) {
#pragma unroll
    for (int o = 32; o > 0; o >>= 1) v += __shfl_xor(v, o, 64);
    return v;
}
__device__ __forceinline__ float wave_max(float v) {
#pragma unroll
    for (int o = 32; o > 0; o >>= 1) v = fmaxf(v, __shfl_xor(v, o, 64));
    return v;
}

__device__ __forceinline__ f32x4 mfma_bf16(bf16x8 a, bf16x8 b, f32x4 c) {
    return __builtin_amdgcn_mfma_f32_16x16x32_bf16(a, b, c, 0, 0, 0);
}

// unpack 8 packed u32 (two uint4) -> hi uint4 + lo uint4 (8 bf16 each)
__device__ __forceinline__ void unpack8(uint4 p0, uint4 p1, uint4& hi, uint4& lo) {
    hi.x = __builtin_amdgcn_perm(p0.y, p0.x, 0x07060302u);
    hi.y = __builtin_amdgcn_perm(p0.w, p0.z, 0x07060302u);
    hi.z = __builtin_amdgcn_perm(p1.y, p1.x, 0x07060302u);
    hi.w = __builtin_amdgcn_perm(p1.w, p1.z, 0x07060302u);
    lo.x = __builtin_amdgcn_perm(p0.y, p0.x, 0x05040100u);
    lo.y = __builtin_amdgcn_perm(p0.w, p0.z, 0x05040100u);
    lo.z = __builtin_amdgcn_perm(p1.y, p1.x, 0x05040100u);
    lo.w = __builtin_amdgcn_perm(p1.w, p1.z, 0x05040100u);
}
__device__ __forceinline__ u32 packpair(float x) {
    u32 u = __float_as_uint(x);
    u32 t = (u + 0x7FFFu + ((u >> 16) & 1u)) & 0xFFFF0000u;
    float lo = x - __uint_as_float(t);
    return t | (__float_as_uint(lo) >> 16);
}

// ---------------------------------------------------------------------------
// Weight prep: W fp32 [K,N] (blockIdx.z batches) -> transposed bf16 hi/lo [N][K]
// ---------------------------------------------------------------------------
__global__ void conv_wt(const float* __restrict__ W, u16* __restrict__ oh,
                        u16* __restrict__ ol, int K, int N)
{
    const long z = blockIdx.z;
    const int idx = blockIdx.x * 256 + threadIdx.x;
    if (idx >= K * N) return;
    const int k = idx / N, n = idx - k * N;
    const float x = W[z * K * N + idx];
    const u16 h = f2bf(x);
    const u16 l = f2bf(x - bf2f(h));
    oh[z * (long)K * N + (long)n * K + k] = h;
    ol[z * (long)K * N + (long)n * K + k] = l;
}

// ---------------------------------------------------------------------------
// bf16x3 MFMA GEMM: C[M,N] = (Ah+Al)[M,K] @ (Bh+Bl)[N,K]^T + bias
// Tile 128x192, BK=32, 256 threads = 4 waves on M.
// Staging via global_load_lds width=16: lane i of a wave covers
// row = group + i/4, 16-B chunk i%4 of the 64-B row.
// EPI 0: fp32 C.  EPI 2: gelu -> hi/lo pair.  EPI 3: hi/lo pair.
// ---------------------------------------------------------------------------
template<int EPI>
__global__ __launch_bounds__(256, 3) void gemm_mfma(
    const u16* __restrict__ Ah, const u16* __restrict__ Al,
    const u16* __restrict__ Bh, const u16* __restrict__ Bl,
    const float* __restrict__ bias,
    float* __restrict__ C, u16* __restrict__ Ch, u16* __restrict__ Cl,
    int N, int K)
{
    __shared__ u16 Ash[128][32];   // 8 KB  (64-B rows, GLL layout)
    __shared__ u16 Als[128][32];   // 8 KB
    __shared__ u16 Bsh[192][32];   // 12 KB
    __shared__ u16 Bsl[192][32];   // 12 KB -> 40 KB total, 3 blocks/CU

    const int tid = threadIdx.x;
    const int wave = tid >> 6, lane = tid & 63;
    const int lm = lane & 15, quad = lane >> 4;
    const long m0 = (long)blockIdx.x * 128;
    const int n0 = blockIdx.y * 192;
    const int lrow = lane >> 2;          // 0..15
    const int lch  = (lane & 3) * 8;     // u16 offset 0,8,16,24 (16-B chunk)

    // per-lane global base pointers (k0 added per iter)
    const u16* pA0h = Ah + (m0 + wave * 32 +  0 + lrow) * K + lch;
    const u16* pA1h = Ah + (m0 + wave * 32 + 16 + lrow) * K + lch;
    const u16* pA0l = Al + (m0 + wave * 32 +  0 + lrow) * K + lch;
    const u16* pA1l = Al + (m0 + wave * 32 + 16 + lrow) * K + lch;
    const u16* pB0h = Bh + (long)(n0 + wave * 48 +  0 + lrow) * K + lch;
    const u16* pB1h = Bh + (long)(n0 + wave * 48 + 16 + lrow) * K + lch;
    const u16* pB2h = Bh + (long)(n0 + wave * 48 + 32 + lrow) * K + lch;
    const u16* pB0l = Bl + (long)(n0 + wave * 48 +  0 + lrow) * K + lch;
    const u16* pB1l = Bl + (long)(n0 + wave * 48 + 16 + lrow) * K + lch;
    const u16* pB2l = Bl + (long)(n0 + wave * 48 + 32 + lrow) * K + lch;

    auto stage = [&](int k0) {
        GLL16(pA0h + k0, &Ash[wave * 32][0]);
        GLL16(pA1h + k0, &Ash[wave * 32 + 16][0]);
        GLL16(pA0l + k0, &Als[wave * 32][0]);
        GLL16(pA1l + k0, &Als[wave * 32 + 16][0]);
        GLL16(pB0h + k0, &Bsh[wave * 48][0]);
        GLL16(pB1h + k0, &Bsh[wave * 48 + 16][0]);
        GLL16(pB2h + k0, &Bsh[wave * 48 + 32][0]);
        GLL16(pB0l + k0, &Bsl[wave * 48][0]);
        GLL16(pB1l + k0, &Bsl[wave * 48 + 16][0]);
        GLL16(pB2l + k0, &Bsl[wave * 48 + 32][0]);
    };

    f32x4 acc[2][12];
#pragma unroll
    for (int i = 0; i < 2; i++)
#pragma unroll
        for (int j = 0; j < 12; j++)
#pragma unroll
            for (int r = 0; r < 4; r++) acc[i][j][r] = 0.f;

    const int kt = K >> 5;
    stage(0);
    __syncthreads();

    for (int t = 0; t < kt; t++) {
        bf16x8 afh[2], afl[2];
#pragma unroll
        for (int mi = 0; mi < 2; mi++) {
            afh[mi] = *(const bf16x8*)&Ash[wave * 32 + mi * 16 + lm][quad * 8];
            afl[mi] = *(const bf16x8*)&Als[wave * 32 + mi * 16 + lm][quad * 8];
        }
#pragma unroll
        for (int g = 0; g < 4; g++) {
            bf16x8 bfh[3], bfl[3];
#pragma unroll
            for (int j = 0; j < 3; j++) {
                bfh[j] = *(const bf16x8*)&Bsh[g * 48 + j * 16 + lm][quad * 8];
                bfl[j] = *(const bf16x8*)&Bsl[g * 48 + j * 16 + lm][quad * 8];
            }
#pragma unroll
            for (int mi = 0; mi < 2; mi++)
#pragma unroll
                for (int j = 0; j < 3; j++) {
                    const int ni = g * 3 + j;
                    acc[mi][ni] = mfma_bf16(afh[mi], bfh[j], acc[mi][ni]);
                    acc[mi][ni] = mfma_bf16(afh[mi], bfl[j], acc[mi][ni]);
                    acc[mi][ni] = mfma_bf16(afl[mi], bfh[j], acc[mi][ni]);
                }
        }
        if (t + 1 < kt) {
            __syncthreads();              // all waves done reading tile t
            stage((t + 1) << 5);
            __syncthreads();              // GLL drained, tile t+1 visible
        }
    }

    // epilogue: C/D layout col = lane&15, row = quad*4 + r
#pragma unroll
    for (int mi = 0; mi < 2; mi++) {
        const long rowb = m0 + wave * 32 + mi * 16 + quad * 4;
#pragma unroll
        for (int ni = 0; ni < 12; ni++) {
            const int col = n0 + ni * 16 + lm;
            const float bv = bias[col];
#pragma unroll
            for (int r = 0; r < 4; r++) {
                float v = acc[mi][ni][r] + bv;
                if (EPI == 0) {
                    C[(rowb + r) * N + col] = v;
                } else {
                    if (EPI == 2) v = gelu_exact(v);
                    const u16 h = f2bf(v);
                    Ch[(rowb + r) * N + col] = h;
                    Cl[(rowb + r) * N + col] = f2bf(v - bf2f(h));
                }
            }
        }
    }
}

// ---------------------------------------------------------------------------
// fp32 GEMM (tokenizer batched + tiny pool GEMMs). Tile 128x64, BK=16.
// ---------------------------------------------------------------------------
template<int EPI>
__global__ __launch_bounds__(256) void gemm_kernel(
    const float* __restrict__ A, int lda, long strideA,
    const float* __restrict__ Bw, long strideB,
    const float* __restrict__ bias, long strideBias,
    float* __restrict__ C, int ldc, long strideC,
    int M, int N, int K, int ldb)
{
    __shared__ float As[16][132];
    __shared__ float Bs[16][68];

    const int z = blockIdx.z;
    const float* Ab    = A    + (long)z * strideA;
    const float* Bb    = Bw   + (long)z * strideB;
    const float* biasb = bias + (long)z * strideBias;
    float*       Cb    = C    + (long)z * strideC;

    const int row0 = blockIdx.x * 128;
    const int col0 = blockIdx.y * 64;
    const int tid  = threadIdx.x;
    const int tm = tid >> 4;
    const int tn = tid & 15;

    const int la_m = tid >> 1;
    const int la_k = (tid & 1) * 8;
    const int lb_k = tid >> 4;
    const int lb_n = (tid & 15) * 4;

    const float* bcol = Bb + (col0 + lb_n);
    const float* arow = Ab + (long)(row0 + la_m) * lda;
    const bool vecA = ((lda & 3) == 0) &&
                      ((((unsigned long long)(const void*)arow) & 15ull) == 0ull);

    float acc[8][4];
#pragma unroll
    for (int i = 0; i < 8; i++)
#pragma unroll
        for (int j = 0; j < 4; j++) acc[i][j] = 0.f;

    for (int k0 = 0; k0 < K; k0 += 16) {
        if (vecA && (k0 + 16 <= K)) {
            float4 v0 = *(const float4*)(arow + k0 + la_k);
            float4 v1 = *(const float4*)(arow + k0 + la_k + 4);
            As[la_k + 0][la_m] = v0.x; As[la_k + 1][la_m] = v0.y;
            As[la_k + 2][la_m] = v0.z; As[la_k + 3][la_m] = v0.w;
            As[la_k + 4][la_m] = v1.x; As[la_k + 5][la_m] = v1.y;
            As[la_k + 6][la_m] = v1.z; As[la_k + 7][la_m] = v1.w;
        } else {
#pragma unroll
            for (int i = 0; i < 8; i++) {
                int k = k0 + la_k + i;
                As[la_k + i][la_m] = (k < K) ? arow[k] : 0.f;
            }
        }
        {
            int k = k0 + lb_k;
            float4 v = make_float4(0.f, 0.f, 0.f, 0.f);
            if (k < K) v = *(const float4*)(bcol + (long)k * ldb);
            *(float4*)&Bs[lb_k][lb_n] = v;
        }
        __syncthreads();
#pragma unroll
        for (int kk = 0; kk < 16; kk++) {
            float4 a0 = *(const float4*)&As[kk][tm * 8];
            float4 a1 = *(const float4*)&As[kk][tm * 8 + 4];
            float4 b4 = *(const float4*)&Bs[kk][tn * 4];
            float av[8] = {a0.x, a0.y, a0.z, a0.w, a1.x, a1.y, a1.z, a1.w};
            float bv[4] = {b4.x, b4.y, b4.z, b4.w};
#pragma unroll
            for (int i = 0; i < 8; i++)
#pragma unroll
                for (int j = 0; j < 4; j++) acc[i][j] += av[i] * bv[j];
        }
        __syncthreads();
    }

    const int gcol = col0 + tn * 4;
    float4 bv4 = *(const float4*)(biasb + gcol);
#pragma unroll
    for (int i = 0; i < 8; i++) {
        int grow = row0 + tm * 8 + i;
        float4 o;
        o.x = acc[i][0] + bv4.x; o.y = acc[i][1] + bv4.y;
        o.z = acc[i][2] + bv4.z; o.w = acc[i][3] + bv4.w;
        if (EPI == 1) {
            o.x = gelu_exact(o.x); o.y = gelu_exact(o.y);
            o.z = gelu_exact(o.z); o.w = gelu_exact(o.w);
        }
        *(float4*)(Cb + (long)grow * ldc + gcol) = o;
    }
}

// ---------------------------------------------------------------------------
// tokenizer post: h = gelu(LN(src; g[r],b[r])) + pos[r] -> hi/lo pair
// 256 threads = 4 waves, one row each.
// ---------------------------------------------------------------------------
__global__ __launch_bounds__(256) void tok_ln_pair(
    const float* __restrict__ src, u16* __restrict__ hh, u16* __restrict__ hl,
    const float* __restrict__ g, const float* __restrict__ bt,
    const float* __restrict__ pos)
{
    const long row = (long)blockIdx.x * 4 + (threadIdx.x >> 6);
    const int r = (int)(row % 200);
    const int l = threadIdx.x & 63;
    const float* sp = src + row * 192;
    float x0 = sp[l], x1 = sp[l + 64], x2 = sp[l + 128];
    float m = wave_sum(x0 + x1 + x2) * (1.f / 192.f);
    float d0 = x0 - m, d1 = x1 - m, d2 = x2 - m;
    float v = wave_sum(d0 * d0 + d1 * d1 + d2 * d2) * (1.f / 192.f);
    float rs = 1.f / sqrtf(v + 1e-5f);
    const float* gr = g + r * 192;
    const float* br = bt + r * 192;
    const float* pr = pos + r * 192;
    const long base = row * 192;
#pragma unroll
    for (int i = 0; i < 3; i++) {
        const int c = l + 64 * i;
        const float d = (i == 0) ? d0 : (i == 1) ? d1 : d2;
        const float y = gelu_exact(d * rs * gr[c] + br[c]) + pr[c];
        const u16 h = f2bf(y);
        hh[base + c] = h;
        hl[base + c] = f2bf(y - bf2f(h));
    }
}

// ---------------------------------------------------------------------------
// h = LN((hh+hl) + a; g, b) -> pair, in place. 4 rows per block.
// ---------------------------------------------------------------------------
__global__ __launch_bounds__(256) void resid_ln_pair(
    u16* __restrict__ hh, u16* __restrict__ hl, const float* __restrict__ a,
    const float* __restrict__ g, const float* __restrict__ bt)
{
    const long row = (long)blockIdx.x * 4 + (threadIdx.x >> 6);
    const int l = threadIdx.x & 63;
    const long base = row * 192;
    float x0 = bf2f(hh[base + l])       + bf2f(hl[base + l])       + a[base + l];
    float x1 = bf2f(hh[base + l + 64])  + bf2f(hl[base + l + 64])  + a[base + l + 64];
    float x2 = bf2f(hh[base + l + 128]) + bf2f(hl[base + l + 128]) + a[base + l + 128];
    float m = wave_sum(x0 + x1 + x2) * (1.f / 192.f);
    float d0 = x0 - m, d1 = x1 - m, d2 = x2 - m;
    float v = wave_sum(d0 * d0 + d1 * d1 + d2 * d2) * (1.f / 192.f);
    float rs = 1.f / sqrtf(v + 1e-5f);
#pragma unroll
    for (int i = 0; i < 3; i++) {
        const int c = l + 64 * i;
        const float d = (i == 0) ? d0 : (i == 1) ? d1 : d2;
        const float y = d * rs * g[c] + bt[c];
        const u16 h = f2bf(y);
        hh[base + c] = h;
        hl[base + c] = f2bf(y - bf2f(h));
    }
}

// ---------------------------------------------------------------------------
// MFMA flash encoder attention. One block per (b,h); 4 waves.
// qkvh/qkvl: [T,576] bf16 pairs.  out: hi/lo pairs [T,192].
// ---------------------------------------------------------------------------
__global__ __launch_bounds__(256, 2) void attn_enc_mfma(
    const u16* __restrict__ qkvh, const u16* __restrict__ qkvl,
    u16* __restrict__ outh, u16* __restrict__ outl)
{
    __shared__ u16 Ksh[96][40];
    __shared__ u16 Ksl[96][40];
    __shared__ u16 Vth[32][120];
    __shared__ u16 Vtl[32][120];
    __shared__ u32 Pbuf[4][16][108];

    const int bh = blockIdx.x;
    const int b = bh / 6, h = bh % 6;
    const int tid = threadIdx.x;
    const int wave = tid >> 6, lane = tid & 63;
    const int lm = lane & 15, quad = lane >> 4;
    const int nq = (wave == 0) ? 4 : 3;   // q-tiles: wave + 4*i (13 total)

    // ---- Q fragments (A-layout: m=lm, k=quad*8+j) ----
    uint4 qh[4], ql[4];
#pragma unroll
    for (int i = 0; i < 4; i++) {
        if (i < nq) {
            int qt = wave + 4 * i;
            int qrow = qt * 16 + lm; if (qrow > 199) qrow = 199;
            const long off = (long)(b * 200 + qrow) * 576 + h * 32 + quad * 8;
            qh[i] = *(const uint4*)(qkvh + off);
            ql[i] = *(const uint4*)(qkvl + off);
        }
    }

    float mrow[4][4], lrow[4][4];
    f32x4 accO[4][2];
#pragma unroll
    for (int i = 0; i < 4; i++)
#pragma unroll
        for (int r = 0; r < 4; r++) {
            mrow[i][r] = -1e30f; lrow[i][r] = 0.f;
            accO[i][0][r] = 0.f; accO[i][1][r] = 0.f;
        }

    const float scale = 0.17677669529663688f;   // 1/sqrt(32)

#pragma unroll
    for (int ph = 0; ph < 3; ph++) {
        const int base = (ph == 0) ? 0 : (ph == 1) ? 96 : 192;
        const int ntl  = (ph == 2) ? 2 : 6;      // 16-key S tiles
        const int nck  = (ph == 2) ? 1 : 3;      // 32-key PV chunks
        const int nslot = ntl * 16;

        __syncthreads();
        if (tid < nslot) {
            const int key = base + tid;
            const bool valid = key < 200;
            const long roff = (long)(b * 200 + (valid ? key : 0)) * 576 + h * 32;
            uint4 z4 = make_uint4(0, 0, 0, 0);
#pragma unroll
            for (int u = 0; u < 4; u++) {
                uint4 kh = valid ? *(const uint4*)(qkvh + roff + 192 + u * 8) : z4;
                uint4 kl = valid ? *(const uint4*)(qkvl + roff + 192 + u * 8) : z4;
                *(uint4*)&Ksh[tid][u * 8] = kh;
                *(uint4*)&Ksl[tid][u * 8] = kl;
                uint4 vh = valid ? *(const uint4*)(qkvh + roff + 384 + u * 8) : z4;
                uint4 vl = valid ? *(const uint4*)(qkvl + roff + 384 + u * 8) : z4;
                const u16* vhp = (const u16*)&vh;
                const u16* vlp = (const u16*)&vl;
#pragma unroll
                for (int j = 0; j < 8; j++) {
                    Vth[u * 8 + j][tid] = vhp[j];
                    Vtl[u * 8 + j][tid] = vlp[j];
                }
            }
        }
        __syncthreads();

#pragma unroll
        for (int i = 0; i < 4; i++) {
            if (i >= nq) continue;
            const bf16x8 qhf = *(const bf16x8*)&qh[i];
            const bf16x8 qlf = *(const bf16x8*)&ql[i];
            float s[6][4];
#pragma unroll
            for (int ni = 0; ni < 6; ni++) {
                if (ni >= ntl) continue;
                bf16x8 kh8 = *(const bf16x8*)&Ksh[ni * 16 + lm][quad * 8];
                bf16x8 kl8 = *(const bf16x8*)&Ksl[ni * 16 + lm][quad * 8];
                f32x4 c = {0.f, 0.f, 0.f, 0.f};
                c = mfma_bf16(qhf, kh8, c);
                c = mfma_bf16(qhf, kl8, c);
                c = mfma_bf16(qlf, kh8, c);
                const bool masked = (base + ni * 16 + lm) >= 200;
#pragma unroll
                for (int r = 0; r < 4; r++)
                    s[ni][r] = masked ? -1e30f : c[r] * scale;
            }
            float fac[4];
#pragma unroll
            for (int r = 0; r < 4; r++) {
                float pm = s[0][r];
#pragma unroll
                for (int ni = 1; ni < 6; ni++)
                    if (ni < ntl) pm = fmaxf(pm, s[ni][r]);
                pm = fmaxf(pm, __shfl_xor(pm, 1, 64));
                pm = fmaxf(pm, __shfl_xor(pm, 2, 64));
                pm = fmaxf(pm, __shfl_xor(pm, 4, 64));
                pm = fmaxf(pm, __shfl_xor(pm, 8, 64));
                const float mn = fmaxf(mrow[i][r], pm);
                fac[r] = __expf(mrow[i][r] - mn);
                mrow[i][r] = mn;
                float ps = 0.f;
#pragma unroll
                for (int ni = 0; ni < 6; ni++) {
                    if (ni >= ntl) continue;
                    float e = __expf(s[ni][r] - mn);
                    s[ni][r] = e;
                    ps += e;
                }
                ps += __shfl_xor(ps, 1, 64);
                ps += __shfl_xor(ps, 2, 64);
                ps += __shfl_xor(ps, 4, 64);
                ps += __shfl_xor(ps, 8, 64);
                lrow[i][r] = lrow[i][r] * fac[r] + ps;
                accO[i][0][r] *= fac[r];
                accO[i][1][r] *= fac[r];
            }
#pragma unroll
            for (int ni = 0; ni < 6; ni++) {
                if (ni >= ntl) continue;
#pragma unroll
                for (int r = 0; r < 4; r++) {
                    Pbuf[wave][quad * 4 + r][ni * 16 + lm] = packpair(s[ni][r]);
                }
            }
#pragma unroll
            for (int ck = 0; ck < 3; ck++) {
                if (ck >= nck) continue;
                uint4 w01 = *(const uint4*)&Pbuf[wave][lm][ck * 32 + quad * 8];
                uint4 w23 = *(const uint4*)&Pbuf[wave][lm][ck * 32 + quad * 8 + 4];
                uint4 hiu, lou;
                unpack8(w01, w23, hiu, lou);
                const bf16x8 phf = *(const bf16x8*)&hiu;
                const bf16x8 plf = *(const bf16x8*)&lou;
#pragma unroll
                for (int nt = 0; nt < 2; nt++) {
                    bf16x8 vh8 = *(const bf16x8*)&Vth[nt * 16 + lm][ck * 32 + quad * 8];
                    bf16x8 vl8 = *(const bf16x8*)&Vtl[nt * 16 + lm][ck * 32 + quad * 8];
                    accO[i][nt] = mfma_bf16(phf, vh8, accO[i][nt]);
                    accO[i][nt] = mfma_bf16(plf, vh8, accO[i][nt]);
                    accO[i][nt] = mfma_bf16(phf, vl8, accO[i][nt]);
                }
            }
        }
    }

    // epilogue: O row = qt*16 + quad*4 + r, col = h*32 + nt*16 + lm (pairs)
#pragma unroll
    for (int i = 0; i < 4; i++) {
        if (i >= nq) continue;
        const int qt = wave + 4 * i;
#pragma unroll
        for (int r = 0; r < 4; r++) {
            const int qrow = qt * 16 + quad * 4 + r;
            if (qrow >= 200) continue;
            const float inv = 1.f / lrow[i][r];
            const long ob = (long)(b * 200 + qrow) * 192 + h * 32 + lm;
            const float v0 = accO[i][0][r] * inv;
            const float v1 = accO[i][1][r] * inv;
            const u16 h0 = f2bf(v0), h1 = f2bf(v1);
            outh[ob]      = h0;
            outl[ob]      = f2bf(v0 - bf2f(h0));
            outh[ob + 16] = h1;
            outl[ob + 16] = f2bf(v1 - bf2f(h1));
        }
    }
}

// ---------------------------------------------------------------------------
__global__ __launch_bounds__(192) void mean_tokens_pair(
    const u16* __restrict__ hh, const u16* __restrict__ hl, float* __restrict__ qmean)
{
    const int b = blockIdx.x, d = threadIdx.x;
    float s = 0.f;
    for (int r = 0; r < 200; r++) {
        const long idx = ((long)b * 200 + r) * 192 + d;
        s += bf2f(hh[idx]) + bf2f(hl[idx]);
    }
    qmean[b * 192 + d] = s * (1.f / 200.f);
}

// ---------------------------------------------------------------------------
// Pooling attention (fp32): qp [256,192], kv [T,384], out [256,192]
// ---------------------------------------------------------------------------
__global__ __launch_bounds__(64) void attn_pool(
    const float* __restrict__ qp, const float* __restrict__ kv,
    float* __restrict__ out)
{
    __shared__ float p[200];
    const int b = blockIdx.x / 6, h = blockIdx.x % 6;
    const int lane = threadIdx.x;

    const float* qrow = qp + b * 192 + h * 32;
    float qr[32];
#pragma unroll
    for (int u = 0; u < 8; u++) {
        float4 t = *(const float4*)(qrow + 4 * u);
        qr[4 * u] = t.x; qr[4 * u + 1] = t.y;
        qr[4 * u + 2] = t.z; qr[4 * u + 3] = t.w;
    }
    const float scale = 0.17677669529663688f;
    const float* kb = kv + (long)(b * 200) * 384 + h * 32;
    float s[4];
    float mymax = -1e30f;
#pragma unroll
    for (int g = 0; g < 4; g++) {
        int j = lane + 64 * g;
        if (j < 200) {
            const float* kr = kb + (long)j * 384;
            float acc = 0.f;
#pragma unroll
            for (int u = 0; u < 8; u++) {
                float4 k4 = *(const float4*)(kr + 4 * u);
                acc += qr[4 * u] * k4.x + qr[4 * u + 1] * k4.y +
                       qr[4 * u + 2] * k4.z + qr[4 * u + 3] * k4.w;
            }
            s[g] = acc * scale;
            mymax = fmaxf(mymax, s[g]);
        } else {
            s[g] = -1e30f;
        }
    }
    float mx = wave_max(mymax);
    float psum = 0.f;
#pragma unroll
    for (int g = 0; g < 4; g++) {
        int j = lane + 64 * g;
        if (j < 200) {
            float e = __expf(s[g] - mx);
            p[j] = e;
            psum += e;
        }
    }
    float tot = wave_sum(psum);
    __syncthreads();
    const int half = lane >> 5, d = lane & 31;
    const float* vb = kv + (long)(b * 200) * 384 + 192 + h * 32 + d;
    float acc = 0.f;
    for (int jj = 0; jj < 100; jj++) {
        int j = half * 100 + jj;
        acc += p[j] * vb[(long)j * 384];
    }
    acc += __shfl_xor(acc, 32, 64);
    acc /= tot;
    if (lane < 32) out[b * 192 + h * 32 + d] = acc;
}

// ---------------------------------------------------------------------------
__global__ __launch_bounds__(64) void classifier_kernel(
    const float* __restrict__ pooled,
    const float* __restrict__ g, const float* __restrict__ bt,
    const float* __restrict__ W1, const float* __restrict__ b1,
    const float* __restrict__ W2, const float* __restrict__ b2,
    const float* __restrict__ W3, const float* __restrict__ b3,
    float* __restrict__ out)
{
    __shared__ float z[192];
    __shared__ float z1[96];
    __shared__ float z2[48];
    const int b = blockIdx.x, lane = threadIdx.x;
    const float* pr = pooled + b * 192;
    float x0 = pr[lane], x1 = pr[lane + 64], x2 = pr[lane + 128];
    float m = wave_sum(x0 + x1 + x2) * (1.f / 192.f);
    float d0 = x0 - m, d1 = x1 - m, d2 = x2 - m;
    float v = wave_sum(d0 * d0 + d1 * d1 + d2 * d2) * (1.f / 192.f);
    float rs = 1.f / sqrtf(v + 1e-5f);
    z[lane]       = d0 * rs * g[lane]       + bt[lane];
    z[lane + 64]  = d1 * rs * g[lane + 64]  + bt[lane + 64];
    z[lane + 128] = d2 * rs * g[lane + 128] + bt[lane + 128];
    __syncthreads();
#pragma unroll
    for (int rep = 0; rep < 2; rep++) {
        int j = lane + rep * 64;
        if (j < 96) {
            float a = b1[j];
            for (int k = 0; k < 192; k++) a += z[k] * W1[k * 96 + j];
            z1[j] = gelu_exact(a);
        }
    }
    __syncthreads();
    if (lane < 48) {
        float a = b2[lane];
        for (int k = 0; k < 96; k++) a += z1[k] * W2[k * 48 + lane];
        z2[lane] = gelu_exact(a);
    }
    __syncthreads();
    if (lane < 2) {
        float a = b3[lane];
        for (int k = 0; k < 48; k++) a += z2[k] * W3[k * 2 + lane];
        out[b * 2 + lane] = a;
    }
}

// ---------------------------------------------------------------------------
extern "C" void kernel_launch(void* const* d_in, const int* in_sizes, int n_in,
                              void* d_out, int out_size, void* d_ws, size_t ws_size,
                              hipStream_t stream)
{
    (void)in_sizes; (void)n_in; (void)out_size; (void)ws_size;

    const float* x         = (const float*)d_in[0];
    const float* roi_W     = (const float*)d_in[1];
    const float* roi_b     = (const float*)d_in[2];
    const float* roi_ln_g  = (const float*)d_in[3];
    const float* roi_ln_b  = (const float*)d_in[4];
    const float* pos_emb   = (const float*)d_in[5];
    const float* enc_Wqkv  = (const float*)d_in[6];
    const float* enc_bqkv  = (const float*)d_in[7];
    const float* enc_Wo    = (const float*)d_in[8];
    const float* enc_bo    = (const float*)d_in[9];
    const float* enc_ln1_g = (const float*)d_in[10];
    const float* enc_ln1_b = (const float*)d_in[11];
    const float* enc_W1    = (const float*)d_in[12];
    const float* enc_b1    = (const float*)d_in[13];
    const float* enc_W2    = (const float*)d_in[14];
    const float* enc_b2    = (const float*)d_in[15];
    const float* enc_ln2_g = (const float*)d_in[16];
    const float* enc_ln2_b = (const float*)d_in[17];
    const float* pool_Wqkv = (const float*)d_in[18];
    const float* pool_bqkv = (const float*)d_in[19];
    const float* pool_Wo   = (const float*)d_in[20];
    const float* pool_bo   = (const float*)d_in[21];
    const float* cls_ln_g  = (const float*)d_in[22];
    const float* cls_ln_b  = (const float*)d_in[23];
    const float* cls_W1    = (const float*)d_in[24];
    const float* cls_b1    = (const float*)d_in[25];
    const float* cls_W2    = (const float*)d_in[26];
    const float* cls_b2    = (const float*)d_in[27];
    const float* cls_W3    = (const float*)d_in[28];
    const float* cls_b3    = (const float*)d_in[29];

    char* ws = (char*)d_ws;
    u16*   hh    = (u16*)(ws);                      // [T,192] hi, 19,660,800 B
    u16*   hl    = (u16*)(ws + 19660800);           // [T,192] lo
    char*  bufA  = ws + 39321600;                   // 117,964,800 B
    float* bufAf = (float*)bufA;
    u16*   qkvh  = (u16*)bufA;                      // [T,576] hi
    u16*   qkvl  = (u16*)(bufA + 58982400);         // [T,576] lo
    u16*   ffh   = (u16*)bufA;                      // reuse after attn
    u16*   ffl   = (u16*)(bufA + 58982400);
    char*  bufB  = ws + 157286400;                  // 39,321,600 B
    u16*   bBh   = (u16*)bufB;                      // attn out hi
    u16*   bBl   = (u16*)(bufB + 19660800);         // attn out lo
    float* bufBf = (float*)bufB;                    // fp32 [T,192]
    float* qmean = (float*)(ws + 196608000);
    float* qp    = qmean + 49152;
    float* pattn = qp + 49152;
    float* pooled= pattn + 49152;
    char*  wts   = ws + 197394432;
    u16* WqkvH = (u16*)(wts);                 // 3*576*192
    u16* WqkvL = (u16*)(wts + 663552);
    u16* Wff1H = (u16*)(wts + 1327104);       // 3*576*192
    u16* Wff1L = (u16*)(wts + 1990656);
    u16* Wff2H = (u16*)(wts + 2654208);       // 3*192*576
    u16* Wff2L = (u16*)(wts + 3317760);
    u16* WwoH  = (u16*)(wts + 3981312);       // 3*192*192
    u16* WwoL  = (u16*)(wts + 4202496);
    u16* WkvH  = (u16*)(wts + 4423680);       // 384*192
    u16* WkvL  = (u16*)(wts + 4571136);

    // ---- weight split/transpose (once per call) ----
    conv_wt<<<dim3(144, 1, 9), 256, 0, stream>>>(enc_Wqkv, WqkvH, WqkvL, 192, 192);
    conv_wt<<<dim3(432, 1, 3), 256, 0, stream>>>(enc_W1, Wff1H, Wff1L, 192, 576);
    conv_wt<<<dim3(432, 1, 3), 256, 0, stream>>>(enc_W2, Wff2H, Wff2L, 576, 192);
    conv_wt<<<dim3(144, 1, 3), 256, 0, stream>>>(enc_Wo, WwoH, WwoL, 192, 192);
    conv_wt<<<dim3(144, 1, 2), 256, 0, stream>>>(pool_Wqkv + 36864, WkvH, WkvL, 192, 192);

    // ---- tokenizer (fp32) -> bufBf [T,192] ----
    gemm_kernel<0><<<dim3(2, 3, 200), 256, 0, stream>>>(
        x, 39800, 199, roi_W, (long)199 * 192, roi_b, 192,
        bufBf, 38400, 192, 256, 192, 199, 192);
    tok_ln_pair<<<12800, 256, 0, stream>>>(bufBf, hh, hl, roi_ln_g, roi_ln_b, pos_emb);

    // ---- encoder layers ----
    for (int i = 0; i < 3; i++) {
        // qkv pairs -> qkvh/qkvl [T,576]
        gemm_mfma<3><<<dim3(400, 3), 256, 0, stream>>>(
            hh, hl, WqkvH + (long)i * 110592, WqkvL + (long)i * 110592,
            enc_bqkv + i * 576, nullptr, qkvh, qkvl, 576, 192);
        // MFMA flash attention -> bBh/bBl pairs [T,192]
        attn_enc_mfma<<<1536, 256, 0, stream>>>(qkvh, qkvl, bBh, bBl);
        // Wo -> bufAf fp32
        gemm_mfma<0><<<dim3(400, 1), 256, 0, stream>>>(
            bBh, bBl, WwoH + (long)i * 36864, WwoL + (long)i * 36864,
            enc_bo + i * 192, bufAf, nullptr, nullptr, 192, 192);
        resid_ln_pair<<<12800, 256, 0, stream>>>(hh, hl, bufAf,
            enc_ln1_g + i * 192, enc_ln1_b + i * 192);
        // ff1 gelu pairs -> ffh/ffl [T,576]
        gemm_mfma<2><<<dim3(400, 3), 256, 0, stream>>>(
            hh, hl, Wff1H + (long)i * 110592, Wff1L + (long)i * 110592,
            enc_b1 + i * 576, nullptr, ffh, ffl, 576, 192);
        // ff2 -> bufBf fp32
        gemm_mfma<0><<<dim3(400, 1), 256, 0, stream>>>(
            ffh, ffl, Wff2H + (long)i * 110592, Wff2L + (long)i * 110592,
            enc_b2 + i * 192, bufBf, nullptr, nullptr, 192, 576);
        resid_ln_pair<<<12800, 256, 0, stream>>>(hh, hl, bufBf,
            enc_ln2_g + i * 192, enc_ln2_b + i * 192);
    }

    // ---- pooling ----
    mean_tokens_pair<<<256, 192, 0, stream>>>(hh, hl, qmean);
    gemm_kernel<0><<<dim3(2, 3, 1), 256, 0, stream>>>(
        qmean, 192, 0, pool_Wqkv, 0, pool_bqkv, 0, qp, 192, 0, 256, 192, 192, 192);
    gemm_mfma<0><<<dim3(400, 2), 256, 0, stream>>>(
        hh, hl, WkvH, WkvL, pool_bqkv + 192,
        bufAf, nullptr, nullptr, 384, 192);
    attn_pool<<<1536, 64, 0, stream>>>(qp, bufAf, pattn);
    gemm_kernel<0><<<dim3(2, 3, 1), 256, 0, stream>>>(
        pattn, 192, 0, pool_Wo, 0, pool_bo, 0, pooled, 192, 0, 256, 192, 192, 192);

    // ---- classifier ----
    classifier_kernel<<<256, 64, 0, stream>>>(
        pooled, cls_ln_g, cls_ln_b,
        cls_W1, cls_b1, cls_W2, cls_b2, cls_W3, cls_b3,
        (float*)d_out);
}

// Round 9
// 1344.450 us; speedup vs baseline: 1.4934x; 1.0801x over previous
//
#include <hip/hip_runtime.h>
#include <math.h>

// B=256, N_ROIS=200, ROI_DIM=199, D=192, H=6, Dh=32, L=3, FF=576, NCLS=2
// T = 51200 tokens.
// GEMMs: bf16x3 split-precision MFMA + global_load_lds width=16 staging.
// Tokenizer: batched MFMA (K padded 199->224) with fused bias+LN+gelu+pos.
// Wo / ff2: fused residual+LN epilogue (N=192 -> full rows per block).

typedef unsigned short u16;
typedef unsigned int u32;
typedef __attribute__((ext_vector_type(8))) __bf16 bf16x8;
typedef __attribute__((ext_vector_type(4))) float f32x4;

#define GLL16(gp, lp) __builtin_amdgcn_global_load_lds(                 \
    (const __attribute__((address_space(1))) void*)(gp),                \
    (__attribute__((address_space(3))) void*)(lp), 16, 0, 0)

__device__ __forceinline__ u16 f2bf(float x) {
    u32 u = __float_as_uint(x);
    u = (u + 0x7FFFu + ((u >> 16) & 1u)) >> 16;   // RNE
    return (u16)u;
}
__device__ __forceinline__ float bf2f(u16 h) {
    return __uint_as_float(((u32)h) << 16);
}

__device__ __forceinline__ float gelu_exact(float x) {
    return 0.5f * x * (1.0f + erff(x * 0.7071067811865475f));
}

__device__ __forceinline__ float wave_sum(float v) {
#pragma unroll
    for (int o = 32; o > 0; o >>= 1) v += __shfl_xor(v, o, 64);
    return v;
}
__device__ __forceinline__ float wave_max(float v) {
#pragma unroll
    for (int o = 32; o > 0; o >>= 1) v = fmaxf(v, __shfl_xor(v, o, 64));
    return v;
}
// reduce across the 16 lanes sharing a quad (row of an MFMA C tile)
__device__ __forceinline__ float row_sum16(float v) {
    v += __shfl_xor(v, 1, 64); v += __shfl_xor(v, 2, 64);
    v += __shfl_xor(v, 4, 64); v += __shfl_xor(v, 8, 64);
    return v;
}

__device__ __forceinline__ f32x4 mfma_bf16(bf16x8 a, bf16x8 b, f32x4 c) {
    return __builtin_amdgcn_mfma_f32_16x16x32_bf16(a, b, c, 0, 0, 0);
}

__device__ __forceinline__ void unpack8(uint4 p0, uint4 p1, uint4& hi, uint4& lo) {
    hi.x = __builtin_amdgcn_perm(p0.y, p0.x, 0x07060302u);
    hi.y = __builtin_amdgcn_perm(p0.w, p0.z, 0x07060302u);
    hi.z = __builtin_amdgcn_perm(p1.y, p1.x, 0x07060302u);
    hi.w = __builtin_amdgcn_perm(p1.w, p1.z, 0x07060302u);
    lo.x = __builtin_amdgcn_perm(p0.y, p0.x, 0x05040100u);
    lo.y = __builtin_amdgcn_perm(p0.w, p0.z, 0x05040100u);
    lo.z = __builtin_amdgcn_perm(p1.y, p1.x, 0x05040100u);
    lo.w = __builtin_amdgcn_perm(p1.w, p1.z, 0x05040100u);
}
__device__ __forceinline__ u32 packpair(float x) {
    u32 u = __float_as_uint(x);
    u32 t = (u + 0x7FFFu + ((u >> 16) & 1u)) & 0xFFFF0000u;
    float lo = x - __uint_as_float(t);
    return t | (__float_as_uint(lo) >> 16);
}

// ---------------------------------------------------------------------------
// Weight prep: W fp32 [K,N] (blockIdx.z batches) -> transposed bf16 hi/lo [N][K]
// ---------------------------------------------------------------------------
__global__ void conv_wt(const float* __restrict__ W, u16* __restrict__ oh,
                        u16* __restrict__ ol, int K, int N)
{
    const long z = blockIdx.z;
    const int idx = blockIdx.x * 256 + threadIdx.x;
    if (idx >= K * N) return;
    const int k = idx / N, n = idx - k * N;
    const float x = W[z * K * N + idx];
    const u16 h = f2bf(x);
    const u16 l = f2bf(x - bf2f(h));
    oh[z * (long)K * N + (long)n * K + k] = h;
    ol[z * (long)K * N + (long)n * K + k] = l;
}

// ---------------------------------------------------------------------------
// x [256][39800] fp32 -> xh/xl [200][256][224] u16 (k>=199 -> 0)
// ---------------------------------------------------------------------------
__global__ void conv_x(const float* __restrict__ x,
                       u16* __restrict__ xh, u16* __restrict__ xl)
{
    const long idx = (long)blockIdx.x * 256 + threadIdx.x;
    if (idx >= 200L * 256 * 224) return;
    const int k = (int)(idx % 224);
    const long t = idx / 224;
    const int m = (int)(t % 256);
    const int z = (int)(t / 256);
    const float v = (k < 199) ? x[(long)m * 39800 + z * 199 + k] : 0.f;
    const u16 h = f2bf(v);
    xh[idx] = h;
    xl[idx] = f2bf(v - bf2f(h));
}

// ---------------------------------------------------------------------------
// roi_W [200][199][192] fp32 -> wth/wtl [200][192][224] (LDS-tiled transpose)
// ---------------------------------------------------------------------------
__global__ void conv_roiw(const float* __restrict__ W,
                          u16* __restrict__ oh, u16* __restrict__ ol)
{
    __shared__ float tile[32][33];
    const int z = blockIdx.z;
    const int k0 = blockIdx.x * 32;   // 7 tiles cover 224
    const int n0 = blockIdx.y * 32;   // 6 tiles cover 192
    for (int i = threadIdx.y; i < 32; i += 8) {
        const int k = k0 + i, n = n0 + threadIdx.x;
        tile[i][threadIdx.x] = (k < 199) ? W[((long)z * 199 + k) * 192 + n] : 0.f;
    }
    __syncthreads();
    for (int i = threadIdx.y; i < 32; i += 8) {
        const int n = n0 + i, k = k0 + threadIdx.x;
        const float v = tile[threadIdx.x][i];
        const u16 h = f2bf(v);
        const long o = ((long)z * 192 + n) * 224 + k;
        oh[o] = h;
        ol[o] = f2bf(v - bf2f(h));
    }
}

// ---------------------------------------------------------------------------
// bf16x3 MFMA GEMM, GLL staging. Tile 128x192, BK=32, 4 waves on M.
// EPI 0: fp32 C.  EPI 2: gelu -> hi/lo pair.  EPI 3: hi/lo pair.
// EPI 5: fused residual+LN: H := LN(H + acc + bias; lng, lnb)  (N must be 192)
// ---------------------------------------------------------------------------
template<int EPI>
__global__ __launch_bounds__(256, 3) void gemm_mfma(
    const u16* __restrict__ Ah, const u16* __restrict__ Al,
    const u16* __restrict__ Bh, const u16* __restrict__ Bl,
    const float* __restrict__ bias,
    float* __restrict__ C, u16* __restrict__ Ch, u16* __restrict__ Cl,
    u16* __restrict__ Hh, u16* __restrict__ Hl,
    const float* __restrict__ lng, const float* __restrict__ lnb,
    int N, int K)
{
    __shared__ u16 Ash[128][32];
    __shared__ u16 Als[128][32];
    __shared__ u16 Bsh[192][32];
    __shared__ u16 Bsl[192][32];

    const int tid = threadIdx.x;
    const int wave = tid >> 6, lane = tid & 63;
    const int lm = lane & 15, quad = lane >> 4;
    const long m0 = (long)blockIdx.x * 128;
    const int n0 = blockIdx.y * 192;
    const int lrow = lane >> 2;
    const int lch  = (lane & 3) * 8;

    const u16* pA0h = Ah + (m0 + wave * 32 +  0 + lrow) * K + lch;
    const u16* pA1h = Ah + (m0 + wave * 32 + 16 + lrow) * K + lch;
    const u16* pA0l = Al + (m0 + wave * 32 +  0 + lrow) * K + lch;
    const u16* pA1l = Al + (m0 + wave * 32 + 16 + lrow) * K + lch;
    const u16* pB0h = Bh + (long)(n0 + wave * 48 +  0 + lrow) * K + lch;
    const u16* pB1h = Bh + (long)(n0 + wave * 48 + 16 + lrow) * K + lch;
    const u16* pB2h = Bh + (long)(n0 + wave * 48 + 32 + lrow) * K + lch;
    const u16* pB0l = Bl + (long)(n0 + wave * 48 +  0 + lrow) * K + lch;
    const u16* pB1l = Bl + (long)(n0 + wave * 48 + 16 + lrow) * K + lch;
    const u16* pB2l = Bl + (long)(n0 + wave * 48 + 32 + lrow) * K + lch;

    auto stage = [&](int k0) {
        GLL16(pA0h + k0, &Ash[wave * 32][0]);
        GLL16(pA1h + k0, &Ash[wave * 32 + 16][0]);
        GLL16(pA0l + k0, &Als[wave * 32][0]);
        GLL16(pA1l + k0, &Als[wave * 32 + 16][0]);
        GLL16(pB0h + k0, &Bsh[wave * 48][0]);
        GLL16(pB1h + k0, &Bsh[wave * 48 + 16][0]);
        GLL16(pB2h + k0, &Bsh[wave * 48 + 32][0]);
        GLL16(pB0l + k0, &Bsl[wave * 48][0]);
        GLL16(pB1l + k0, &Bsl[wave * 48 + 16][0]);
        GLL16(pB2l + k0, &Bsl[wave * 48 + 32][0]);
    };

    f32x4 acc[2][12];
#pragma unroll
    for (int i = 0; i < 2; i++)
#pragma unroll
        for (int j = 0; j < 12; j++)
#pragma unroll
            for (int r = 0; r < 4; r++) acc[i][j][r] = 0.f;

    const int kt = K >> 5;
    stage(0);
    __syncthreads();

    for (int t = 0; t < kt; t++) {
        bf16x8 afh[2], afl[2];
#pragma unroll
        for (int mi = 0; mi < 2; mi++) {
            afh[mi] = *(const bf16x8*)&Ash[wave * 32 + mi * 16 + lm][quad * 8];
            afl[mi] = *(const bf16x8*)&Als[wave * 32 + mi * 16 + lm][quad * 8];
        }
#pragma unroll
        for (int g = 0; g < 4; g++) {
            bf16x8 bfh[3], bfl[3];
#pragma unroll
            for (int j = 0; j < 3; j++) {
                bfh[j] = *(const bf16x8*)&Bsh[g * 48 + j * 16 + lm][quad * 8];
                bfl[j] = *(const bf16x8*)&Bsl[g * 48 + j * 16 + lm][quad * 8];
            }
#pragma unroll
            for (int mi = 0; mi < 2; mi++)
#pragma unroll
                for (int j = 0; j < 3; j++) {
                    const int ni = g * 3 + j;
                    acc[mi][ni] = mfma_bf16(afh[mi], bfh[j], acc[mi][ni]);
                    acc[mi][ni] = mfma_bf16(afh[mi], bfl[j], acc[mi][ni]);
                    acc[mi][ni] = mfma_bf16(afl[mi], bfh[j], acc[mi][ni]);
                }
        }
        if (t + 1 < kt) {
            __syncthreads();
            stage((t + 1) << 5);
            __syncthreads();
        }
    }

    if (EPI == 5) {
        // fused residual + LN, in place on Hh/Hl (N==192, one block per rows)
        float gv[12], bv2[12], biasv[12];
#pragma unroll
        for (int ni = 0; ni < 12; ni++) {
            const int col = ni * 16 + lm;
            gv[ni] = lng[col]; bv2[ni] = lnb[col]; biasv[ni] = bias[col];
        }
#pragma unroll
        for (int mi = 0; mi < 2; mi++) {
#pragma unroll
            for (int r = 0; r < 4; r++) {
                const long row = m0 + wave * 32 + mi * 16 + quad * 4 + r;
                const long rb = row * 192;
                float vals[12];
                float s = 0.f;
#pragma unroll
                for (int ni = 0; ni < 12; ni++) {
                    const int col = ni * 16 + lm;
                    const float hval = bf2f(Hh[rb + col]) + bf2f(Hl[rb + col]);
                    vals[ni] = acc[mi][ni][r] + biasv[ni] + hval;
                    s += vals[ni];
                }
                const float mean = row_sum16(s) * (1.f / 192.f);
                float ss = 0.f;
#pragma unroll
                for (int ni = 0; ni < 12; ni++) {
                    vals[ni] -= mean;
                    ss += vals[ni] * vals[ni];
                }
                const float var = row_sum16(ss) * (1.f / 192.f);
                const float rsr = 1.f / sqrtf(var + 1e-5f);
#pragma unroll
                for (int ni = 0; ni < 12; ni++) {
                    const int col = ni * 16 + lm;
                    const float y = vals[ni] * rsr * gv[ni] + bv2[ni];
                    const u16 hb = f2bf(y);
                    Hh[rb + col] = hb;
                    Hl[rb + col] = f2bf(y - bf2f(hb));
                }
            }
        }
        return;
    }

#pragma unroll
    for (int mi = 0; mi < 2; mi++) {
        const long rowb = m0 + wave * 32 + mi * 16 + quad * 4;
#pragma unroll
        for (int ni = 0; ni < 12; ni++) {
            const int col = n0 + ni * 16 + lm;
            const float bv = bias[col];
#pragma unroll
            for (int r = 0; r < 4; r++) {
                float v = acc[mi][ni][r] + bv;
                if (EPI == 0) {
                    C[(rowb + r) * N + col] = v;
                } else {
                    if (EPI == 2) v = gelu_exact(v);
                    const u16 h = f2bf(v);
                    Ch[(rowb + r) * N + col] = h;
                    Cl[(rowb + r) * N + col] = f2bf(v - bf2f(h));
                }
            }
        }
    }
}

// ---------------------------------------------------------------------------
// Tokenizer MFMA: per-z GEMM [256,224]@[192,224]^T with fused
// bias + LN + gelu + pos epilogue -> hh/hl at [b][z][d].
// grid (2, 200): blockIdx.x = m-tile, blockIdx.y = z (ROI).
// ---------------------------------------------------------------------------
__global__ __launch_bounds__(256, 3) void tok_mfma(
    const u16* __restrict__ xh, const u16* __restrict__ xl,
    const u16* __restrict__ wth, const u16* __restrict__ wtl,
    const float* __restrict__ roi_b,
    const float* __restrict__ lng, const float* __restrict__ lnb,
    const float* __restrict__ pos,
    u16* __restrict__ hh, u16* __restrict__ hl)
{
    __shared__ u16 Ash[128][32];
    __shared__ u16 Als[128][32];
    __shared__ u16 Bsh[192][32];
    __shared__ u16 Bsl[192][32];

    const int tid = threadIdx.x;
    const int wave = tid >> 6, lane = tid & 63;
    const int lm = lane & 15, quad = lane >> 4;
    const int m0 = blockIdx.x * 128;
    const int z = blockIdx.y;
    const int lrow = lane >> 2;
    const int lch  = (lane & 3) * 8;
    const int K = 224;

    const u16* pA0h = xh + ((long)z * 256 + m0 + wave * 32 +  0 + lrow) * K + lch;
    const u16* pA1h = xh + ((long)z * 256 + m0 + wave * 32 + 16 + lrow) * K + lch;
    const u16* pA0l = xl + ((long)z * 256 + m0 + wave * 32 +  0 + lrow) * K + lch;
    const u16* pA1l = xl + ((long)z * 256 + m0 + wave * 32 + 16 + lrow) * K + lch;
    const u16* pB0h = wth + ((long)z * 192 + wave * 48 +  0 + lrow) * K + lch;
    const u16* pB1h = wth + ((long)z * 192 + wave * 48 + 16 + lrow) * K + lch;
    const u16* pB2h = wth + ((long)z * 192 + wave * 48 + 32 + lrow) * K + lch;
    const u16* pB0l = wtl + ((long)z * 192 + wave * 48 +  0 + lrow) * K + lch;
    const u16* pB1l = wtl + ((long)z * 192 + wave * 48 + 16 + lrow) * K + lch;
    const u16* pB2l = wtl + ((long)z * 192 + wave * 48 + 32 + lrow) * K + lch;

    auto stage = [&](int k0) {
        GLL16(pA0h + k0, &Ash[wave * 32][0]);
        GLL16(pA1h + k0, &Ash[wave * 32 + 16][0]);
        GLL16(pA0l + k0, &Als[wave * 32][0]);
        GLL16(pA1l + k0, &Als[wave * 32 + 16][0]);
        GLL16(pB0h + k0, &Bsh[wave * 48][0]);
        GLL16(pB1h + k0, &Bsh[wave * 48 + 16][0]);
        GLL16(pB2h + k0, &Bsh[wave * 48 + 32][0]);
        GLL16(pB0l + k0, &Bsl[wave * 48][0]);
        GLL16(pB1l + k0, &Bsl[wave * 48 + 16][0]);
        GLL16(pB2l + k0, &Bsl[wave * 48 + 32][0]);
    };

    f32x4 acc[2][12];
#pragma unroll
    for (int i = 0; i < 2; i++)
#pragma unroll
        for (int j = 0; j < 12; j++)
#pragma unroll
            for (int r = 0; r < 4; r++) acc[i][j][r] = 0.f;

    stage(0);
    __syncthreads();
    for (int t = 0; t < 7; t++) {
        bf16x8 afh[2], afl[2];
#pragma unroll
        for (int mi = 0; mi < 2; mi++) {
            afh[mi] = *(const bf16x8*)&Ash[wave * 32 + mi * 16 + lm][quad * 8];
            afl[mi] = *(const bf16x8*)&Als[wave * 32 + mi * 16 + lm][quad * 8];
        }
#pragma unroll
        for (int g = 0; g < 4; g++) {
            bf16x8 bfh[3], bfl[3];
#pragma unroll
            for (int j = 0; j < 3; j++) {
                bfh[j] = *(const bf16x8*)&Bsh[g * 48 + j * 16 + lm][quad * 8];
                bfl[j] = *(const bf16x8*)&Bsl[g * 48 + j * 16 + lm][quad * 8];
            }
#pragma unroll
            for (int mi = 0; mi < 2; mi++)
#pragma unroll
                for (int j = 0; j < 3; j++) {
                    const int ni = g * 3 + j;
                    acc[mi][ni] = mfma_bf16(afh[mi], bfh[j], acc[mi][ni]);
                    acc[mi][ni] = mfma_bf16(afh[mi], bfl[j], acc[mi][ni]);
                    acc[mi][ni] = mfma_bf16(afl[mi], bfh[j], acc[mi][ni]);
                }
        }
        if (t + 1 < 7) {
            __syncthreads();
            stage((t + 1) << 5);
            __syncthreads();
        }
    }

    // fused epilogue: tok = gelu(LN(acc + roi_b)) + pos
    float gv[12], bv2[12], biasv[12], pv[12];
#pragma unroll
    for (int ni = 0; ni < 12; ni++) {
        const int col = ni * 16 + lm;
        gv[ni]    = lng[z * 192 + col];
        bv2[ni]   = lnb[z * 192 + col];
        biasv[ni] = roi_b[z * 192 + col];
        pv[ni]    = pos[z * 192 + col];
    }
#pragma unroll
    for (int mi = 0; mi < 2; mi++) {
#pragma unroll
        for (int r = 0; r < 4; r++) {
            const int brow = m0 + wave * 32 + mi * 16 + quad * 4 + r;  // batch
            float vals[12];
            float s = 0.f;
#pragma unroll
            for (int ni = 0; ni < 12; ni++) {
                vals[ni] = acc[mi][ni][r] + biasv[ni];
                s += vals[ni];
            }
            const float mean = row_sum16(s) * (1.f / 192.f);
            float ss = 0.f;
#pragma unroll
            for (int ni = 0; ni < 12; ni++) {
                vals[ni] -= mean;
                ss += vals[ni] * vals[ni];
            }
            const float var = row_sum16(ss) * (1.f / 192.f);
            const float rsr = 1.f / sqrtf(var + 1e-5f);
            const long ob = ((long)brow * 200 + z) * 192;
#pragma unroll
            for (int ni = 0; ni < 12; ni++) {
                const int col = ni * 16 + lm;
                const float y = gelu_exact(vals[ni] * rsr * gv[ni] + bv2[ni]) + pv[ni];
                const u16 hb = f2bf(y);
                hh[ob + col] = hb;
                hl[ob + col] = f2bf(y - bf2f(hb));
            }
        }
    }
}

// ---------------------------------------------------------------------------
// fp32 GEMM (tiny pool GEMMs). Tile 128x64, BK=16.
// ---------------------------------------------------------------------------
template<int EPI>
__global__ __launch_bounds__(256) void gemm_kernel(
    const float* __restrict__ A, int lda, long strideA,
    const float* __restrict__ Bw, long strideB,
    const float* __restrict__ bias, long strideBias,
    float* __restrict__ C, int ldc, long strideC,
    int M, int N, int K, int ldb)
{
    __shared__ float As[16][132];
    __shared__ float Bs[16][68];

    const int z = blockIdx.z;
    const float* Ab    = A    + (long)z * strideA;
    const float* Bb    = Bw   + (long)z * strideB;
    const float* biasb = bias + (long)z * strideBias;
    float*       Cb    = C    + (long)z * strideC;

    const int row0 = blockIdx.x * 128;
    const int col0 = blockIdx.y * 64;
    const int tid  = threadIdx.x;
    const int tm = tid >> 4;
    const int tn = tid & 15;

    const int la_m = tid >> 1;
    const int la_k = (tid & 1) * 8;
    const int lb_k = tid >> 4;
    const int lb_n = (tid & 15) * 4;

    const float* bcol = Bb + (col0 + lb_n);
    const float* arow = Ab + (long)(row0 + la_m) * lda;
    const bool vecA = ((lda & 3) == 0) &&
                      ((((unsigned long long)(const void*)arow) & 15ull) == 0ull);

    float acc[8][4];
#pragma unroll
    for (int i = 0; i < 8; i++)
#pragma unroll
        for (int j = 0; j < 4; j++) acc[i][j] = 0.f;

    for (int k0 = 0; k0 < K; k0 += 16) {
        if (vecA && (k0 + 16 <= K)) {
            float4 v0 = *(const float4*)(arow + k0 + la_k);
            float4 v1 = *(const float4*)(arow + k0 + la_k + 4);
            As[la_k + 0][la_m] = v0.x; As[la_k + 1][la_m] = v0.y;
            As[la_k + 2][la_m] = v0.z; As[la_k + 3][la_m] = v0.w;
            As[la_k + 4][la_m] = v1.x; As[la_k + 5][la_m] = v1.y;
            As[la_k + 6][la_m] = v1.z; As[la_k + 7][la_m] = v1.w;
        } else {
#pragma unroll
            for (int i = 0; i < 8; i++) {
                int k = k0 + la_k + i;
                As[la_k + i][la_m] = (k < K) ? arow[k] : 0.f;
            }
        }
        {
            int k = k0 + lb_k;
            float4 v = make_float4(0.f, 0.f, 0.f, 0.f);
            if (k < K) v = *(const float4*)(bcol + (long)k * ldb);
            *(float4*)&Bs[lb_k][lb_n] = v;
        }
        __syncthreads();
#pragma unroll
        for (int kk = 0; kk < 16; kk++) {
            float4 a0 = *(const float4*)&As[kk][tm * 8];
            float4 a1 = *(const float4*)&As[kk][tm * 8 + 4];
            float4 b4 = *(const float4*)&Bs[kk][tn * 4];
            float av[8] = {a0.x, a0.y, a0.z, a0.w, a1.x, a1.y, a1.z, a1.w};
            float bv[4] = {b4.x, b4.y, b4.z, b4.w};
#pragma unroll
            for (int i = 0; i < 8; i++)
#pragma unroll
                for (int j = 0; j < 4; j++) acc[i][j] += av[i] * bv[j];
        }
        __syncthreads();
    }

    const int gcol = col0 + tn * 4;
    float4 bv4 = *(const float4*)(biasb + gcol);
#pragma unroll
    for (int i = 0; i < 8; i++) {
        int grow = row0 + tm * 8 + i;
        float4 o;
        o.x = acc[i][0] + bv4.x; o.y = acc[i][1] + bv4.y;
        o.z = acc[i][2] + bv4.z; o.w = acc[i][3] + bv4.w;
        if (EPI == 1) {
            o.x = gelu_exact(o.x); o.y = gelu_exact(o.y);
            o.z = gelu_exact(o.z); o.w = gelu_exact(o.w);
        }
        *(float4*)(Cb + (long)grow * ldc + gcol) = o;
    }
}

// ---------------------------------------------------------------------------
// MFMA flash encoder attention (unchanged from R8).
// ---------------------------------------------------------------------------
__global__ __launch_bounds__(256, 2) void attn_enc_mfma(
    const u16* __restrict__ qkvh, const u16* __restrict__ qkvl,
    u16* __restrict__ outh, u16* __restrict__ outl)
{
    __shared__ u16 Ksh[96][40];
    __shared__ u16 Ksl[96][40];
    __shared__ u16 Vth[32][120];
    __shared__ u16 Vtl[32][120];
    __shared__ u32 Pbuf[4][16][108];

    const int bh = blockIdx.x;
    const int b = bh / 6, h = bh % 6;
    const int tid = threadIdx.x;
    const int wave = tid >> 6, lane = tid & 63;
    const int lm = lane & 15, quad = lane >> 4;
    const int nq = (wave == 0) ? 4 : 3;

    uint4 qh[4], ql[4];
#pragma unroll
    for (int i = 0; i < 4; i++) {
        if (i < nq) {
            int qt = wave + 4 * i;
            int qrow = qt * 16 + lm; if (qrow > 199) qrow = 199;
            const long off = (long)(b * 200 + qrow) * 576 + h * 32 + quad * 8;
            qh[i] = *(const uint4*)(qkvh + off);
            ql[i] = *(const uint4*)(qkvl + off);
        }
    }

    float mrow[4][4], lrow[4][4];
    f32x4 accO[4][2];
#pragma unroll
    for (int i = 0; i < 4; i++)
#pragma unroll
        for (int r = 0; r < 4; r++) {
            mrow[i][r] = -1e30f; lrow[i][r] = 0.f;
            accO[i][0][r] = 0.f; accO[i][1][r] = 0.f;
        }

    const float scale = 0.17677669529663688f;

#pragma unroll
    for (int ph = 0; ph < 3; ph++) {
        const int base = (ph == 0) ? 0 : (ph == 1) ? 96 : 192;
        const int ntl  = (ph == 2) ? 2 : 6;
        const int nck  = (ph == 2) ? 1 : 3;
        const int nslot = ntl * 16;

        __syncthreads();
        if (tid < nslot) {
            const int key = base + tid;
            const bool valid = key < 200;
            const long roff = (long)(b * 200 + (valid ? key : 0)) * 576 + h * 32;
            uint4 z4 = make_uint4(0, 0, 0, 0);
#pragma unroll
            for (int u = 0; u < 4; u++) {
                uint4 kh = valid ? *(const uint4*)(qkvh + roff + 192 + u * 8) : z4;
                uint4 kl = valid ? *(const uint4*)(qkvl + roff + 192 + u * 8) : z4;
                *(uint4*)&Ksh[tid][u * 8] = kh;
                *(uint4*)&Ksl[tid][u * 8] = kl;
                uint4 vh = valid ? *(const uint4*)(qkvh + roff + 384 + u * 8) : z4;
                uint4 vl = valid ? *(const uint4*)(qkvl + roff + 384 + u * 8) : z4;
                const u16* vhp = (const u16*)&vh;
                const u16* vlp = (const u16*)&vl;
#pragma unroll
                for (int j = 0; j < 8; j++) {
                    Vth[u * 8 + j][tid] = vhp[j];
                    Vtl[u * 8 + j][tid] = vlp[j];
                }
            }
        }
        __syncthreads();

#pragma unroll
        for (int i = 0; i < 4; i++) {
            if (i >= nq) continue;
            const bf16x8 qhf = *(const bf16x8*)&qh[i];
            const bf16x8 qlf = *(const bf16x8*)&ql[i];
            float s[6][4];
#pragma unroll
            for (int ni = 0; ni < 6; ni++) {
                if (ni >= ntl) continue;
                bf16x8 kh8 = *(const bf16x8*)&Ksh[ni * 16 + lm][quad * 8];
                bf16x8 kl8 = *(const bf16x8*)&Ksl[ni * 16 + lm][quad * 8];
                f32x4 c = {0.f, 0.f, 0.f, 0.f};
                c = mfma_bf16(qhf, kh8, c);
                c = mfma_bf16(qhf, kl8, c);
                c = mfma_bf16(qlf, kh8, c);
                const bool masked = (base + ni * 16 + lm) >= 200;
#pragma unroll
                for (int r = 0; r < 4; r++)
                    s[ni][r] = masked ? -1e30f : c[r] * scale;
            }
            float fac[4];
#pragma unroll
            for (int r = 0; r < 4; r++) {
                float pm = s[0][r];
#pragma unroll
                for (int ni = 1; ni < 6; ni++)
                    if (ni < ntl) pm = fmaxf(pm, s[ni][r]);
                pm = fmaxf(pm, __shfl_xor(pm, 1, 64));
                pm = fmaxf(pm, __shfl_xor(pm, 2, 64));
                pm = fmaxf(pm, __shfl_xor(pm, 4, 64));
                pm = fmaxf(pm, __shfl_xor(pm, 8, 64));
                const float mn = fmaxf(mrow[i][r], pm);
                fac[r] = __expf(mrow[i][r] - mn);
                mrow[i][r] = mn;
                float ps = 0.f;
#pragma unroll
                for (int ni = 0; ni < 6; ni++) {
                    if (ni >= ntl) continue;
                    float e = __expf(s[ni][r] - mn);
                    s[ni][r] = e;
                    ps += e;
                }
                ps += __shfl_xor(ps, 1, 64);
                ps += __shfl_xor(ps, 2, 64);
                ps += __shfl_xor(ps, 4, 64);
                ps += __shfl_xor(ps, 8, 64);
                lrow[i][r] = lrow[i][r] * fac[r] + ps;
                accO[i][0][r] *= fac[r];
                accO[i][1][r] *= fac[r];
            }
#pragma unroll
            for (int ni = 0; ni < 6; ni++) {
                if (ni >= ntl) continue;
#pragma unroll
                for (int r = 0; r < 4; r++) {
                    Pbuf[wave][quad * 4 + r][ni * 16 + lm] = packpair(s[ni][r]);
                }
            }
#pragma unroll
            for (int ck = 0; ck < 3; ck++) {
                if (ck >= nck) continue;
                uint4 w01 = *(const uint4*)&Pbuf[wave][lm][ck * 32 + quad * 8];
                uint4 w23 = *(const uint4*)&Pbuf[wave][lm][ck * 32 + quad * 8 + 4];
                uint4 hiu, lou;
                unpack8(w01, w23, hiu, lou);
                const bf16x8 phf = *(const bf16x8*)&hiu;
                const bf16x8 plf = *(const bf16x8*)&lou;
#pragma unroll
                for (int nt = 0; nt < 2; nt++) {
                    bf16x8 vh8 = *(const bf16x8*)&Vth[nt * 16 + lm][ck * 32 + quad * 8];
                    bf16x8 vl8 = *(const bf16x8*)&Vtl[nt * 16 + lm][ck * 32 + quad * 8];
                    accO[i][nt] = mfma_bf16(phf, vh8, accO[i][nt]);
                    accO[i][nt] = mfma_bf16(plf, vh8, accO[i][nt]);
                    accO[i][nt] = mfma_bf16(phf, vl8, accO[i][nt]);
                }
            }
        }
    }

#pragma unroll
    for (int i = 0; i < 4; i++) {
        if (i >= nq) continue;
        const int qt = wave + 4 * i;
#pragma unroll
        for (int r = 0; r < 4; r++) {
            const int qrow = qt * 16 + quad * 4 + r;
            if (qrow >= 200) continue;
            const float inv = 1.f / lrow[i][r];
            const long ob = (long)(b * 200 + qrow) * 192 + h * 32 + lm;
            const float v0 = accO[i][0][r] * inv;
            const float v1 = accO[i][1][r] * inv;
            const u16 h0 = f2bf(v0), h1 = f2bf(v1);
            outh[ob]      = h0;
            outl[ob]      = f2bf(v0 - bf2f(h0));
            outh[ob + 16] = h1;
            outl[ob + 16] = f2bf(v1 - bf2f(h1));
        }
    }
}

// ---------------------------------------------------------------------------
__global__ __launch_bounds__(192) void mean_tokens_pair(
    const u16* __restrict__ hh, const u16* __restrict__ hl, float* __restrict__ qmean)
{
    const int b = blockIdx.x, d = threadIdx.x;
    float s = 0.f;
    for (int r = 0; r < 200; r++) {
        const long idx = ((long)b * 200 + r) * 192 + d;
        s += bf2f(hh[idx]) + bf2f(hl[idx]);
    }
    qmean[b * 192 + d] = s * (1.f / 200.f);
}

// ---------------------------------------------------------------------------
__global__ __launch_bounds__(64) void attn_pool(
    const float* __restrict__ qp, const float* __restrict__ kv,
    float* __restrict__ out)
{
    __shared__ float p[200];
    const int b = blockIdx.x / 6, h = blockIdx.x % 6;
    const int lane = threadIdx.x;

    const float* qrow = qp + b * 192 + h * 32;
    float qr[32];
#pragma unroll
    for (int u = 0; u < 8; u++) {
        float4 t = *(const float4*)(qrow + 4 * u);
        qr[4 * u] = t.x; qr[4 * u + 1] = t.y;
        qr[4 * u + 2] = t.z; qr[4 * u + 3] = t.w;
    }
    const float scale = 0.17677669529663688f;
    const float* kb = kv + (long)(b * 200) * 384 + h * 32;
    float s[4];
    float mymax = -1e30f;
#pragma unroll
    for (int g = 0; g < 4; g++) {
        int j = lane + 64 * g;
        if (j < 200) {
            const float* kr = kb + (long)j * 384;
            float acc = 0.f;
#pragma unroll
            for (int u = 0; u < 8; u++) {
                float4 k4 = *(const float4*)(kr + 4 * u);
                acc += qr[4 * u] * k4.x + qr[4 * u + 1] * k4.y +
                       qr[4 * u + 2] * k4.z + qr[4 * u + 3] * k4.w;
            }
            s[g] = acc * scale;
            mymax = fmaxf(mymax, s[g]);
        } else {
            s[g] = -1e30f;
        }
    }
    float mx = wave_max(mymax);
    float psum = 0.f;
#pragma unroll
    for (int g = 0; g < 4; g++) {
        int j = lane + 64 * g;
        if (j < 200) {
            float e = __expf(s[g] - mx);
            p[j] = e;
            psum += e;
        }
    }
    float tot = wave_sum(psum);
    __syncthreads();
    const int half = lane >> 5, d = lane & 31;
    const float* vb = kv + (long)(b * 200) * 384 + 192 + h * 32 + d;
    float acc = 0.f;
    for (int jj = 0; jj < 100; jj++) {
        int j = half * 100 + jj;
        acc += p[j] * vb[(long)j * 384];
    }
    acc += __shfl_xor(acc, 32, 64);
    acc /= tot;
    if (lane < 32) out[b * 192 + h * 32 + d] = acc;
}

// ---------------------------------------------------------------------------
__global__ __launch_bounds__(64) void classifier_kernel(
    const float* __restrict__ pooled,
    const float* __restrict__ g, const float* __restrict__ bt,
    const float* __restrict__ W1, const float* __restrict__ b1,
    const float* __restrict__ W2, const float* __restrict__ b2,
    const float* __restrict__ W3, const float* __restrict__ b3,
    float* __restrict__ out)
{
    __shared__ float z[192];
    __shared__ float z1[96];
    __shared__ float z2[48];
    const int b = blockIdx.x, lane = threadIdx.x;
    const float* pr = pooled + b * 192;
    float x0 = pr[lane], x1 = pr[lane + 64], x2 = pr[lane + 128];
    float m = wave_sum(x0 + x1 + x2) * (1.f / 192.f);
    float d0 = x0 - m, d1 = x1 - m, d2 = x2 - m;
    float v = wave_sum(d0 * d0 + d1 * d1 + d2 * d2) * (1.f / 192.f);
    float rs = 1.f / sqrtf(v + 1e-5f);
    z[lane]       = d0 * rs * g[lane]       + bt[lane];
    z[lane + 64]  = d1 * rs * g[lane + 64]  + bt[lane + 64];
    z[lane + 128] = d2 * rs * g[lane + 128] + bt[lane + 128];
    __syncthreads();
#pragma unroll
    for (int rep = 0; rep < 2; rep++) {
        int j = lane + rep * 64;
        if (j < 96) {
            float a = b1[j];
            for (int k = 0; k < 192; k++) a += z[k] * W1[k * 96 + j];
            z1[j] = gelu_exact(a);
        }
    }
    __syncthreads();
    if (lane < 48) {
        float a = b2[lane];
        for (int k = 0; k < 96; k++) a += z1[k] * W2[k * 48 + lane];
        z2[lane] = gelu_exact(a);
    }
    __syncthreads();
    if (lane < 2) {
        float a = b3[lane];
        for (int k = 0; k < 48; k++) a += z2[k] * W3[k * 2 + lane];
        out[b * 2 + lane] = a;
    }
}

// ---------------------------------------------------------------------------
extern "C" void kernel_launch(void* const* d_in, const int* in_sizes, int n_in,
                              void* d_out, int out_size, void* d_ws, size_t ws_size,
                              hipStream_t stream)
{
    (void)in_sizes; (void)n_in; (void)out_size; (void)ws_size;

    const float* x         = (const float*)d_in[0];
    const float* roi_W     = (const float*)d_in[1];
    const float* roi_b     = (const float*)d_in[2];
    const float* roi_ln_g  = (const float*)d_in[3];
    const float* roi_ln_b  = (const float*)d_in[4];
    const float* pos_emb   = (const float*)d_in[5];
    const float* enc_Wqkv  = (const float*)d_in[6];
    const float* enc_bqkv  = (const float*)d_in[7];
    const float* enc_Wo    = (const float*)d_in[8];
    const float* enc_bo    = (const float*)d_in[9];
    const float* enc_ln1_g = (const float*)d_in[10];
    const float* enc_ln1_b = (const float*)d_in[11];
    const float* enc_W1    = (const float*)d_in[12];
    const float* enc_b1    = (const float*)d_in[13];
    const float* enc_W2    = (const float*)d_in[14];
    const float* enc_b2    = (const float*)d_in[15];
    const float* enc_ln2_g = (const float*)d_in[16];
    const float* enc_ln2_b = (const float*)d_in[17];
    const float* pool_Wqkv = (const float*)d_in[18];
    const float* pool_bqkv = (const float*)d_in[19];
    const float* pool_Wo   = (const float*)d_in[20];
    const float* pool_bo   = (const float*)d_in[21];
    const float* cls_ln_g  = (const float*)d_in[22];
    const float* cls_ln_b  = (const float*)d_in[23];
    const float* cls_W1    = (const float*)d_in[24];
    const float* cls_b1    = (const float*)d_in[25];
    const float* cls_W2    = (const float*)d_in[26];
    const float* cls_b2    = (const float*)d_in[27];
    const float* cls_W3    = (const float*)d_in[28];
    const float* cls_b3    = (const float*)d_in[29];

    char* ws = (char*)d_ws;
    u16*   hh    = (u16*)(ws);                      // [T,192] hi
    u16*   hl    = (u16*)(ws + 19660800);           // [T,192] lo
    char*  bufA  = ws + 39321600;                   // 117,964,800 B
    float* bufAf = (float*)bufA;
    // tokenizer-phase layout of bufA:
    u16*   xh    = (u16*)bufA;                      // 200*256*224 = 22,937,600 B
    u16*   xl    = (u16*)(bufA + 22937600);
    u16*   wth   = (u16*)(bufA + 45875200);         // 200*192*224 = 17,203,200 B
    u16*   wtl   = (u16*)(bufA + 63078400);
    // encoder-phase layout of bufA:
    u16*   qkvh  = (u16*)bufA;                      // [T,576] hi
    u16*   qkvl  = (u16*)(bufA + 58982400);         // [T,576] lo
    u16*   ffh   = (u16*)bufA;
    u16*   ffl   = (u16*)(bufA + 58982400);
    char*  bufB  = ws + 157286400;                  // 39,321,600 B
    u16*   bBh   = (u16*)bufB;
    u16*   bBl   = (u16*)(bufB + 19660800);
    float* qmean = (float*)(ws + 196608000);
    float* qp    = qmean + 49152;
    float* pattn = qp + 49152;
    float* pooled= pattn + 49152;
    char*  wts   = ws + 197394432;
    u16* WqkvH = (u16*)(wts);
    u16* WqkvL = (u16*)(wts + 663552);
    u16* Wff1H = (u16*)(wts + 1327104);
    u16* Wff1L = (u16*)(wts + 1990656);
    u16* Wff2H = (u16*)(wts + 2654208);
    u16* Wff2L = (u16*)(wts + 3317760);
    u16* WwoH  = (u16*)(wts + 3981312);
    u16* WwoL  = (u16*)(wts + 4202496);
    u16* WkvH  = (u16*)(wts + 4423680);
    u16* WkvL  = (u16*)(wts + 4571136);

    // ---- weight split/transpose (once per call) ----
    conv_wt<<<dim3(144, 1, 9), 256, 0, stream>>>(enc_Wqkv, WqkvH, WqkvL, 192, 192);
    conv_wt<<<dim3(432, 1, 3), 256, 0, stream>>>(enc_W1, Wff1H, Wff1L, 192, 576);
    conv_wt<<<dim3(432, 1, 3), 256, 0, stream>>>(enc_W2, Wff2H, Wff2L, 576, 192);
    conv_wt<<<dim3(144, 1, 3), 256, 0, stream>>>(enc_Wo, WwoH, WwoL, 192, 192);
    conv_wt<<<dim3(144, 1, 2), 256, 0, stream>>>(pool_Wqkv + 36864, WkvH, WkvL, 192, 192);

    // ---- tokenizer: split + batched MFMA with fused LN/gelu/pos ----
    conv_x<<<44800, 256, 0, stream>>>(x, xh, xl);
    conv_roiw<<<dim3(7, 6, 200), dim3(32, 8), 0, stream>>>(roi_W, wth, wtl);
    tok_mfma<<<dim3(2, 200), 256, 0, stream>>>(
        xh, xl, wth, wtl, roi_b, roi_ln_g, roi_ln_b, pos_emb, hh, hl);

    // ---- encoder layers ----
    for (int i = 0; i < 3; i++) {
        // qkv pairs -> qkvh/qkvl [T,576]
        gemm_mfma<3><<<dim3(400, 3), 256, 0, stream>>>(
            hh, hl, WqkvH + (long)i * 110592, WqkvL + (long)i * 110592,
            enc_bqkv + i * 576, nullptr, qkvh, qkvl,
            nullptr, nullptr, nullptr, nullptr, 576, 192);
        // MFMA flash attention -> bBh/bBl pairs [T,192]
        attn_enc_mfma<<<1536, 256, 0, stream>>>(qkvh, qkvl, bBh, bBl);
        // Wo + fused residual LN1 (in place on hh/hl)
        gemm_mfma<5><<<dim3(400, 1), 256, 0, stream>>>(
            bBh, bBl, WwoH + (long)i * 36864, WwoL + (long)i * 36864,
            enc_bo + i * 192, nullptr, nullptr, nullptr,
            hh, hl, enc_ln1_g + i * 192, enc_ln1_b + i * 192, 192, 192);
        // ff1 gelu pairs -> ffh/ffl [T,576]
        gemm_mfma<2><<<dim3(400, 3), 256, 0, stream>>>(
            hh, hl, Wff1H + (long)i * 110592, Wff1L + (long)i * 110592,
            enc_b1 + i * 576, nullptr, ffh, ffl,
            nullptr, nullptr, nullptr, nullptr, 576, 192);
        // ff2 + fused residual LN2 (in place on hh/hl)
        gemm_mfma<5><<<dim3(400, 1), 256, 0, stream>>>(
            ffh, ffl, Wff2H + (long)i * 110592, Wff2L + (long)i * 110592,
            enc_b2 + i * 192, nullptr, nullptr, nullptr,
            hh, hl, enc_ln2_g + i * 192, enc_ln2_b + i * 192, 192, 576);
    }

    // ---- pooling ----
    mean_tokens_pair<<<256, 192, 0, stream>>>(hh, hl, qmean);
    gemm_kernel<0><<<dim3(2, 3, 1), 256, 0, stream>>>(
        qmean, 192, 0, pool_Wqkv, 0, pool_bqkv, 0, qp, 192, 0, 256, 192, 192, 192);
    gemm_mfma<0><<<dim3(400, 2), 256, 0, stream>>>(
        hh, hl, WkvH, WkvL, pool_bqkv + 192,
        bufAf, nullptr, nullptr,
        nullptr, nullptr, nullptr, nullptr, 384, 192);
    attn_pool<<<1536, 64, 0, stream>>>(qp, bufAf, pattn);
    gemm_kernel<0><<<dim3(2, 3, 1), 256, 0, stream>>>(
        pattn, 192, 0, pool_Wo, 0, pool_bo, 0, pooled, 192, 0, 256, 192, 192, 192);

    // ---- classifier ----
    classifier_kernel<<<256, 64, 0, stream>>>(
        pooled, cls_ln_g, cls_ln_b,
        cls_W1, cls_b1, cls_W2, cls_b2, cls_W3, cls_b3,
        (float*)d_out);
}